// Round 14
// baseline (1331.082 us; speedup 1.0000x reference)
//
#include <hip/hip_runtime.h>
#include <cstdint>
#include <cstddef>

using u16 = unsigned short;
using bf16x8 = __attribute__((ext_vector_type(8))) short;
using f32x4  = __attribute__((ext_vector_type(4))) float;

__device__ __forceinline__ u16 f2bf(float f) {
  unsigned u = __float_as_uint(f);
  u += 0x7fffu + ((u >> 16) & 1u);
  return (u16)(u >> 16);
}
__device__ __forceinline__ float bf2f(u16 h) {
  return __uint_as_float(((unsigned)h) << 16);
}

__device__ __forceinline__ void gload_lds16(const void* g, void* l) {
  auto gp = reinterpret_cast<const __attribute__((address_space(1))) char*>(
      reinterpret_cast<uintptr_t>(g));
  auto lp = reinterpret_cast<__attribute__((address_space(3))) char*>(
      reinterpret_cast<uintptr_t>(l));
  __builtin_amdgcn_global_load_lds(gp, lp, 16, 0, 0);
}

// ---------- weight transpose + downcast: W f32[din][dout] -> WT bf16[dout][din]
__global__ __launch_bounds__(256) void transpose_to_bf16(
    const float* __restrict__ W, u16* __restrict__ WT, int din, int dout) {
  __shared__ float tile[32][33];
  const int j0 = blockIdx.x * 32;   // dout
  const int i0 = blockIdx.y * 32;   // din
  const int tx = threadIdx.x & 31;
  const int ty = threadIdx.x >> 5;  // 0..7
#pragma unroll
  for (int k = 0; k < 32; k += 8)
    tile[ty + k][tx] = W[(size_t)(i0 + ty + k) * dout + (j0 + tx)];
  __syncthreads();
#pragma unroll
  for (int k = 0; k < 32; k += 8)
    WT[(size_t)(j0 + ty + k) * din + (i0 + tx)] = f2bf(tile[tx][ty + k]);
}

// ---------- rmsnorm f32 -> bf16, one block per row of 1024
__global__ __launch_bounds__(256) void rmsnorm_kernel(
    const float* __restrict__ x, const float* __restrict__ g, u16* __restrict__ xn) {
  const int row = blockIdx.x;
  const float4 v = ((const float4*)(x + (size_t)row * 1024))[threadIdx.x];
  float ss = v.x * v.x + v.y * v.y + v.z * v.z + v.w * v.w;
#pragma unroll
  for (int off = 32; off > 0; off >>= 1) ss += __shfl_down(ss, off, 64);
  __shared__ float red[4];
  if ((threadIdx.x & 63) == 0) red[threadIdx.x >> 6] = ss;
  __syncthreads();
  const float rs = rsqrtf((red[0] + red[1] + red[2] + red[3]) * (1.f / 1024.f) + 1e-6f);
  const float4 gv = ((const float4*)g)[threadIdx.x];
  ushort4 o;
  o.x = f2bf(v.x * rs * gv.x);
  o.y = f2bf(v.y * rs * gv.y);
  o.z = f2bf(v.z * rs * gv.z);
  o.w = f2bf(v.w * rs * gv.w);
  ((ushort4*)(xn + (size_t)row * 1024))[threadIdx.x] = o;
}

// ---------- chunked linear-recurrence scan: h[l] = sig(-dt)*h[l-1] + sig(dt)*sig(lnz)
__global__ __launch_bounds__(256) void scan_pass1(
    const u16* __restrict__ dt, const u16* __restrict__ lnz,
    float* __restrict__ P, float* __restrict__ S) {
  const int blk = blockIdx.x;              // B*64*4 = 1024 blocks
  const int dblk = blk & 3;
  const int chunk = (blk >> 2) & 63;
  const int b = blk >> 8;
  const int d = dblk * 256 + threadIdx.x;
  const size_t base = ((size_t)b * 4096 + (size_t)chunk * 64) * 1024 + d;
  float p = 1.f, s = 0.f;
#pragma unroll 8
  for (int l = 0; l < 64; ++l) {
    const float dtv = bf2f(dt[base + (size_t)l * 1024]);
    const float zv = bf2f(lnz[base + (size_t)l * 1024]);
    const float a = 1.f / (1.f + __expf(dtv));        // sigmoid(-dt)
    const float zs = 1.f / (1.f + __expf(-zv));       // sigmoid(lnz_pre)
    const float in = (1.f - a) * zs;
    p *= a;
    s = a * s + in;
  }
  const size_t o = ((size_t)b * 64 + chunk) * 1024 + d;
  P[o] = p;
  S[o] = s;
}

__global__ __launch_bounds__(256) void scan_pass2(
    const float* __restrict__ P, const float* __restrict__ S,
    const float* __restrict__ hidden, float* __restrict__ hin) {
  const int idx = blockIdx.x * 256 + threadIdx.x;  // 0..4095
  const int b = idx >> 10, d = idx & 1023;
  float h = hidden[idx];
#pragma unroll 8
  for (int c = 0; c < 64; ++c) {
    const size_t o = ((size_t)b * 64 + c) * 1024 + d;
    hin[o] = h;
    h = P[o] * h + S[o];
  }
}

__global__ __launch_bounds__(256) void scan_pass3(
    const u16* __restrict__ dt, const u16* __restrict__ lnz,
    const float* __restrict__ hin, float* __restrict__ h_out, u16* __restrict__ hbf) {
  const int blk = blockIdx.x;
  const int dblk = blk & 3;
  const int chunk = (blk >> 2) & 63;
  const int b = blk >> 8;
  const int d = dblk * 256 + threadIdx.x;
  const size_t base = ((size_t)b * 4096 + (size_t)chunk * 64) * 1024 + d;
  float h = hin[((size_t)b * 64 + chunk) * 1024 + d];
#pragma unroll 4
  for (int l = 0; l < 64; ++l) {
    const float dtv = bf2f(dt[base + (size_t)l * 1024]);
    const float zv = bf2f(lnz[base + (size_t)l * 1024]);
    const float a = 1.f / (1.f + __expf(dtv));
    const float zs = 1.f / (1.f + __expf(-zv));
    h = a * h + (1.f - a) * zs;
    h_out[base + (size_t)l * 1024] = h;
    hbf[base + (size_t)l * 1024] = f2bf(h);
  }
}

// ---------- 256x128 GEMM, A-in-LDS + B-from-global: C = A[M][K] @ B^T (bf16).
// B panel per block is 16 KiB/tile, shared by 8 waves -> L1-resident; B
// fragments load straight to registers (lanes r,r+16,r+32,r+48 hit one 64B
// line). Only A is staged (global_load_lds), ring of 5 x 16 KiB A-halves
// (80 KiB -> 2 blocks/CU, m114 cross-block overlap).
// Ring advances +2/tile; stage targets (2t+2)%5,(2t+3)%5 = tile t-1's slots,
// dead since the t-1 end barrier -> ONE barrier per K-tile, and the tile-end
// vmcnt(0) is free (in-order vmcnt: B-loads consumed by MFMA retire older
// stage loads first).
// 4Mx2N waves (wave tile 64x64); acc[4][4] (64 AGPR); bR holds 2 n-frags
// (B read in 2 bursts, A frags re-read per burst — LDS reads not binding, R13).
// EPI: 5 = fused3: bf16 outs {outH=dt, outH2=lnz, outH3=yg}, row stride 1024
//      2 = f32 out = (acc+b)*silu(gate bf16) + resid
//      6 = bf16 out = silu(acc+b)
//      7 = bf16 out = (acc+b)*bf2f(gate)   (gate may alias outH: in-place)
//      4 = f32 out = acc + b + outF (in-place residual add)
template <int EPI>
__global__ __launch_bounds__(512, 4) void gemm256(
    const u16* __restrict__ A, const u16* __restrict__ B,
    const float* __restrict__ bias, const u16* __restrict__ gate,
    const float* __restrict__ resid, float* __restrict__ outF,
    u16* __restrict__ outH, u16* __restrict__ outH2, u16* __restrict__ outH3,
    int ntx, int N, int K) {
  constexpr int SLOT = 16384;
  const int tid = threadIdx.x;
  const int lane = tid & 63;
  const int wid = tid >> 6;
  const int wrow = wid >> 1;   // 0..3 -> 64-row strip of the 256-row tile
  const int wcol = wid & 1;    // 0..1 -> 64-col strip of the 128-col tile
  const int whalf = wrow >> 1; // A-half slot select
  const int wsub  = wrow & 1;  // 64-row strip within the 128-row half

  // XCD-aware swizzle (grid %8==0 for all our launches)
  const int nwg = gridDim.x;
  int id = blockIdx.x;
  id = (id & 7) * (nwg >> 3) + (id >> 3);
  const int m0 = (id / ntx) * 256;
  const int n0 = (id % ntx) * 128;

  __shared__ __align__(16) char lds[5 * SLOT];

  f32x4 acc[4][4];   // [m-frag][n-frag] over the wave's 64x64 tile
#pragma unroll
  for (int m = 0; m < 4; ++m)
#pragma unroll
    for (int n = 0; n < 4; ++n) acc[m][n] = (f32x4){0.f, 0.f, 0.f, 0.f};

  bf16x8 aR[2];      // one m-frag (2 k) at a time
  bf16x8 bR[2][2];   // 2 n-frags (current burst) x 2 k

  // ---- A LDS read base (m-frag at +m*2048, k=1 at ^64 — swizzle bits
  //      invariant under +16 rows; bit 6 disjoint) ----
  int aOff0;
  {
    const int lq = (lane >> 4) << 4;
    const int hr = wsub * 64 + (lane & 15);
    aOff0 = hr * 128 + (lq ^ ((hr & 7) << 4));
  }

  // ---- B global fragment pointers: row = n0+wcol*64+j*16+(lane&15),
  //      byte-in-row = (lane>>4)*16 (+64 for k=1, imm). Advance +128/tile. ----
  const char* pBf[4];
#pragma unroll
  for (int j = 0; j < 4; ++j)
    pBf[j] = (const char*)B +
             (size_t)(n0 + wcol * 64 + j * 16 + (lane & 15)) * K * 2 +
             ((lane >> 4) << 4);

  // ---- A stage addressing ----
  const int row0 = tid >> 3;                               // 0..63
  const int kb0  = ((tid & 7) * 16) ^ ((row0 & 7) << 4);   // inverse-swizzled src byte
  const size_t dRow = (size_t)128 * K;                     // +64 rows (bytes)
  const char* pA0 = (const char*)A + (size_t)(m0 + row0) * K * 2 + kb0;
  const char* pA1 = pA0 + (size_t)256 * K;                 // +128 rows
  const int ldst = tid * 16;                               // LDS offset within slot

#define STAGE(PTR, SB)                                                        \
  {                                                                           \
    gload_lds16(PTR, lds + (SB) + ldst);                                      \
    gload_lds16(PTR + dRow, lds + (SB) + ldst + 8192);                        \
    PTR += 128;                                                               \
  }

#define READA(SAB, Q)                                                         \
  {                                                                           \
    const int _o = aOff0 + (Q) * 2048;                                        \
    aR[0] = *(const bf16x8*)(lds + (SAB) + _o);                               \
    aR[1] = *(const bf16x8*)(lds + (SAB) + (_o ^ 64));                        \
  }

#define READBG(H)                                                             \
  _Pragma("unroll") for (int n = 0; n < 2; ++n) {                             \
    const char* _p = pBf[(H) * 2 + n];                                        \
    bR[n][0] = *(const bf16x8*)_p;                                            \
    bR[n][1] = *(const bf16x8*)(_p + 64);                                     \
  }

#define MMAH(Q, H)                                                            \
  __builtin_amdgcn_s_setprio(1);                                              \
  _Pragma("unroll") for (int n = 0; n < 2; ++n)                               \
  _Pragma("unroll") for (int k = 0; k < 2; ++k)                               \
      acc[Q][(H) * 2 + n] = __builtin_amdgcn_mfma_f32_16x16x32_bf16(          \
          aR[k], bR[n][k], acc[Q][(H) * 2 + n], 0, 0, 0);                     \
  __builtin_amdgcn_s_setprio(0);

  const int NT = K >> 6;

  // prologue: tile0's A halves -> slots 0,1
  STAGE(pA0, 0 * SLOT);
  STAGE(pA1, 1 * SLOT);
  asm volatile("s_waitcnt vmcnt(0)" ::: "memory");
  __builtin_amdgcn_s_barrier();

  int iA0 = 0;   // slot of tile t's A0 half; advances +2 mod 5

  for (int t = 0; t < NT; ++t) {
    int ra = iA0 + whalf; if (ra >= 5) ra -= 5;
    const int sAb = __builtin_amdgcn_readfirstlane(ra * SLOT);
    int s2 = iA0 + 2; if (s2 >= 5) s2 -= 5;   // A0(t+1) -> dead A0(t-1)
    int s3 = iA0 + 3; if (s3 >= 5) s3 -= 5;   // A1(t+1) -> dead A1(t-1)
    const bool st = (t < NT - 1);
    // burst 0: B n-frags 0,1 from global (L1-hot), stages early (dead slots)
    READBG(0);
    if (st) {
      STAGE(pA0, s2 * SLOT);
      STAGE(pA1, s3 * SLOT);
    }
    READA(sAb, 0); MMAH(0, 0);
    READA(sAb, 1); MMAH(1, 0);
    READA(sAb, 2); MMAH(2, 0);
    READA(sAb, 3); MMAH(3, 0);
    // burst 1: B n-frags 2,3
    READBG(1);
    READA(sAb, 0); MMAH(0, 1);
    READA(sAb, 1); MMAH(1, 1);
    READA(sAb, 2); MMAH(2, 1);
    READA(sAb, 3); MMAH(3, 1);
#pragma unroll
    for (int j = 0; j < 4; ++j) pBf[j] += 128;
    // stages (oldest VMEM) already retired by the B-load waits -> free drain
    asm volatile("s_waitcnt vmcnt(0)" ::: "memory");
    __builtin_amdgcn_s_barrier();
    iA0 += 2; if (iA0 >= 5) iA0 -= 5;
  }

  // epilogue: C/D layout col = lane&15, row = (lane>>4)*4 + j
#pragma unroll
  for (int m = 0; m < 4; ++m) {
#pragma unroll
    for (int n = 0; n < 4; ++n) {
      const int col = n0 + wcol * 64 + n * 16 + (lane & 15);
#pragma unroll
      for (int j = 0; j < 4; ++j) {
        const int row = m0 + wrow * 64 + m * 16 + ((lane >> 4) << 2) + j;
        const float v = acc[m][n][j] + bias[col];
        if constexpr (EPI == 5) {
          const int rg = col >> 10;                     // block-uniform
          const size_t o = (size_t)row * 1024 + (col & 1023);
          if (rg == 0) outH[o] = f2bf(v);
          else if (rg == 1) outH2[o] = f2bf(v);
          else outH3[o] = f2bf(v);
        } else {
          const size_t o = (size_t)row * N + col;
          if constexpr (EPI == 2) {
            const float gt = bf2f(gate[o]);
            outF[o] = v * (gt / (1.f + __expf(-gt))) + resid[o];
          } else if constexpr (EPI == 6) {
            outH[o] = f2bf(v / (1.f + __expf(-v)));
          } else if constexpr (EPI == 7) {
            outH[o] = f2bf(v * bf2f(gate[o]));          // gate==outH ok (RAW per elem)
          } else if constexpr (EPI == 4) {
            outF[o] = v + outF[o];
          }
        }
      }
    }
  }
#undef STAGE
#undef READA
#undef READBG
#undef MMAH
}

extern "C" void kernel_launch(void* const* d_in, const int* in_sizes, int n_in,
                              void* d_out, int out_size, void* d_ws, size_t ws_size,
                              hipStream_t stream) {
  const float* x      = (const float*)d_in[0];
  const float* hidden = (const float*)d_in[1];
  const float* w_ln_z = (const float*)d_in[2];
  const float* b_ln_z = (const float*)d_in[3];
  const float* w_dt   = (const float*)d_in[4];
  const float* b_dt   = (const float*)d_in[5];
  const float* w_y    = (const float*)d_in[6];
  const float* b_y    = (const float*)d_in[7];
  const float* w_yg   = (const float*)d_in[8];
  const float* b_yg   = (const float*)d_in[9];
  const float* w_ff   = (const float*)d_in[10];
  const float* b_ff   = (const float*)d_in[11];
  const float* w_ffg  = (const float*)d_in[12];
  const float* b_ffg  = (const float*)d_in[13];
  const float* w_ffo  = (const float*)d_in[14];
  const float* b_ffo  = (const float*)d_in[15];
  const float* g_sio  = (const float*)d_in[16];
  const float* g_ffn  = (const float*)d_in[17];

  char* ws = (char*)d_ws;
  const size_t MB = 1ull << 20;
  u16*   WT_cat = (u16*)(ws + 0 * MB);      // 6 MiB  [3072][1024] (dt|lnz|yg)
  u16*   WT_y   = (u16*)(ws + 8 * MB);      // 2 MiB
  u16*   WT_ff  = (u16*)(ws + 10 * MB);     // 8 MiB  [4096][1024]
  u16*   WT_ffg = (u16*)(ws + 18 * MB);     // 8 MiB
  u16*   WT_ffo = (u16*)(ws + 26 * MB);     // 8 MiB  [1024][4096]
  float* b_cat  = (float*)(ws + 34 * MB);   // 12 KiB [3072]
  u16*   xn     = (u16*)(ws + 36 * MB);     // 32 MiB [16384][1024] bf16
  u16*   dt16   = (u16*)(ws + 68 * MB);     // 32 MiB bf16
  u16*   lnzb   = (u16*)(ws + 100 * MB);    // 32 MiB
  u16*   ygb    = (u16*)(ws + 132 * MB);    // 32 MiB
  u16*   hbf    = (u16*)(ws + 164 * MB);    // 32 MiB
  float* Pc     = (float*)(ws + 196 * MB);  // 1 MiB
  float* Sc     = (float*)(ws + 197 * MB);  // 1 MiB
  float* hin    = (float*)(ws + 198 * MB);  // 1 MiB
  u16*   gs     = (u16*)(ws + 68 * MB);     // 128 MiB overlay [16384][4096]
  // peak ws usage: 199 MiB

  float* x_out = (float*)d_out;
  float* h_out = (float*)d_out + (size_t)4 * 4096 * 1024;

  const int M = 16384, D = 1024, F = 4096;
  const dim3 tb(256);

  transpose_to_bf16<<<dim3(32, 32), tb, 0, stream>>>(w_dt, WT_cat, D, D);
  transpose_to_bf16<<<dim3(32, 32), tb, 0, stream>>>(w_ln_z, WT_cat + 1024 * 1024, D, D);
  transpose_to_bf16<<<dim3(32, 32), tb, 0, stream>>>(w_yg, WT_cat + 2 * 1024 * 1024, D, D);
  transpose_to_bf16<<<dim3(32, 32), tb, 0, stream>>>(w_y, WT_y, D, D);
  transpose_to_bf16<<<dim3(128, 32), tb, 0, stream>>>(w_ff, WT_ff, D, F);
  transpose_to_bf16<<<dim3(128, 32), tb, 0, stream>>>(w_ffg, WT_ffg, D, F);
  transpose_to_bf16<<<dim3(32, 128), tb, 0, stream>>>(w_ffo, WT_ffo, F, D);
  (void)hipMemcpyAsync(b_cat, b_dt, D * 4, hipMemcpyDeviceToDevice, stream);
  (void)hipMemcpyAsync(b_cat + 1024, b_ln_z, D * 4, hipMemcpyDeviceToDevice, stream);
  (void)hipMemcpyAsync(b_cat + 2048, b_yg, D * 4, hipMemcpyDeviceToDevice, stream);

  rmsnorm_kernel<<<M, tb, 0, stream>>>(x, g_sio, xn);

  // fused dt|lnz|yg GEMM: N=3072, ntx=24
  gemm256<5><<<dim3(64 * 24), 512, 0, stream>>>(xn, WT_cat, b_cat, nullptr, nullptr,
                                                nullptr, dt16, lnzb, ygb, 24, 3072, D);

  scan_pass1<<<1024, tb, 0, stream>>>(dt16, lnzb, Pc, Sc);
  scan_pass2<<<16, tb, 0, stream>>>(Pc, Sc, hidden, hin);
  scan_pass3<<<1024, tb, 0, stream>>>(dt16, lnzb, hin, h_out, hbf);

  // x1 = (h@w_y + b_y) * silu(yg) + x   (N=1024, ntx=8)
  gemm256<2><<<dim3(64 * 8), 512, 0, stream>>>(hbf, WT_y, b_y, ygb, x,
                                               x_out, nullptr, nullptr, nullptr, 8, D, D);

  rmsnorm_kernel<<<M, tb, 0, stream>>>(x_out, g_ffn, xn);

  // gs = silu(xn@w_ffg + b_ffg)   (N=4096, ntx=32)
  gemm256<6><<<dim3(64 * 32), 512, 0, stream>>>(xn, WT_ffg, b_ffg, nullptr, nullptr,
                                                nullptr, gs, nullptr, nullptr, 32, F, D);
  // gs = (xn@w_ff + b_ff) * gs   (in-place gated mul)
  gemm256<7><<<dim3(64 * 32), 512, 0, stream>>>(xn, WT_ff, b_ff, gs, nullptr,
                                                nullptr, gs, nullptr, nullptr, 32, F, D);
  // x_out += gs@w_ffo + b_ffo   (N=1024, ntx=8, K=4096)
  gemm256<4><<<dim3(64 * 8), 512, 0, stream>>>(gs, WT_ffo, b_ffo, nullptr, nullptr,
                                               x_out, nullptr, nullptr, nullptr, 8, D, F);
}

// Round 15
// 847.296 us; speedup vs baseline: 1.5710x; 1.5710x over previous
//
#include <hip/hip_runtime.h>
#include <cstdint>
#include <cstddef>

using u16 = unsigned short;
using bf16x8 = __attribute__((ext_vector_type(8))) short;
using f32x4  = __attribute__((ext_vector_type(4))) float;

__device__ __forceinline__ u16 f2bf(float f) {
  unsigned u = __float_as_uint(f);
  u += 0x7fffu + ((u >> 16) & 1u);
  return (u16)(u >> 16);
}
__device__ __forceinline__ float bf2f(u16 h) {
  return __uint_as_float(((unsigned)h) << 16);
}

__device__ __forceinline__ void gload_lds16(const void* g, void* l) {
  auto gp = reinterpret_cast<const __attribute__((address_space(1))) char*>(
      reinterpret_cast<uintptr_t>(g));
  auto lp = reinterpret_cast<__attribute__((address_space(3))) char*>(
      reinterpret_cast<uintptr_t>(l));
  __builtin_amdgcn_global_load_lds(gp, lp, 16, 0, 0);
}

// ---------- weight transpose + downcast: W f32[din][dout] -> WT bf16[dout][din]
__global__ __launch_bounds__(256) void transpose_to_bf16(
    const float* __restrict__ W, u16* __restrict__ WT, int din, int dout) {
  __shared__ float tile[32][33];
  const int j0 = blockIdx.x * 32;   // dout
  const int i0 = blockIdx.y * 32;   // din
  const int tx = threadIdx.x & 31;
  const int ty = threadIdx.x >> 5;  // 0..7
#pragma unroll
  for (int k = 0; k < 32; k += 8)
    tile[ty + k][tx] = W[(size_t)(i0 + ty + k) * dout + (j0 + tx)];
  __syncthreads();
#pragma unroll
  for (int k = 0; k < 32; k += 8)
    WT[(size_t)(j0 + ty + k) * din + (i0 + tx)] = f2bf(tile[tx][ty + k]);
}

// ---------- rmsnorm f32 -> bf16, one block per row of 1024
__global__ __launch_bounds__(256) void rmsnorm_kernel(
    const float* __restrict__ x, const float* __restrict__ g, u16* __restrict__ xn) {
  const int row = blockIdx.x;
  const float4 v = ((const float4*)(x + (size_t)row * 1024))[threadIdx.x];
  float ss = v.x * v.x + v.y * v.y + v.z * v.z + v.w * v.w;
#pragma unroll
  for (int off = 32; off > 0; off >>= 1) ss += __shfl_down(ss, off, 64);
  __shared__ float red[4];
  if ((threadIdx.x & 63) == 0) red[threadIdx.x >> 6] = ss;
  __syncthreads();
  const float rs = rsqrtf((red[0] + red[1] + red[2] + red[3]) * (1.f / 1024.f) + 1e-6f);
  const float4 gv = ((const float4*)g)[threadIdx.x];
  ushort4 o;
  o.x = f2bf(v.x * rs * gv.x);
  o.y = f2bf(v.y * rs * gv.y);
  o.z = f2bf(v.z * rs * gv.z);
  o.w = f2bf(v.w * rs * gv.w);
  ((ushort4*)(xn + (size_t)row * 1024))[threadIdx.x] = o;
}

// ---------- chunked linear-recurrence scan: h[l] = sig(-dt)*h[l-1] + sig(dt)*sig(lnz)
__global__ __launch_bounds__(256) void scan_pass1(
    const u16* __restrict__ dt, const u16* __restrict__ lnz,
    float* __restrict__ P, float* __restrict__ S) {
  const int blk = blockIdx.x;              // B*64*4 = 1024 blocks
  const int dblk = blk & 3;
  const int chunk = (blk >> 2) & 63;
  const int b = blk >> 8;
  const int d = dblk * 256 + threadIdx.x;
  const size_t base = ((size_t)b * 4096 + (size_t)chunk * 64) * 1024 + d;
  float p = 1.f, s = 0.f;
#pragma unroll 8
  for (int l = 0; l < 64; ++l) {
    const float dtv = bf2f(dt[base + (size_t)l * 1024]);
    const float zv = bf2f(lnz[base + (size_t)l * 1024]);
    const float a = 1.f / (1.f + __expf(dtv));        // sigmoid(-dt)
    const float zs = 1.f / (1.f + __expf(-zv));       // sigmoid(lnz_pre)
    const float in = (1.f - a) * zs;
    p *= a;
    s = a * s + in;
  }
  const size_t o = ((size_t)b * 64 + chunk) * 1024 + d;
  P[o] = p;
  S[o] = s;
}

__global__ __launch_bounds__(256) void scan_pass2(
    const float* __restrict__ P, const float* __restrict__ S,
    const float* __restrict__ hidden, float* __restrict__ hin) {
  const int idx = blockIdx.x * 256 + threadIdx.x;  // 0..4095
  const int b = idx >> 10, d = idx & 1023;
  float h = hidden[idx];
#pragma unroll 8
  for (int c = 0; c < 64; ++c) {
    const size_t o = ((size_t)b * 64 + c) * 1024 + d;
    hin[o] = h;
    h = P[o] * h + S[o];
  }
}

__global__ __launch_bounds__(256) void scan_pass3(
    const u16* __restrict__ dt, const u16* __restrict__ lnz,
    const float* __restrict__ hin, float* __restrict__ h_out, u16* __restrict__ hbf) {
  const int blk = blockIdx.x;
  const int dblk = blk & 3;
  const int chunk = (blk >> 2) & 63;
  const int b = blk >> 8;
  const int d = dblk * 256 + threadIdx.x;
  const size_t base = ((size_t)b * 4096 + (size_t)chunk * 64) * 1024 + d;
  float h = hin[((size_t)b * 64 + chunk) * 1024 + d];
#pragma unroll 4
  for (int l = 0; l < 64; ++l) {
    const float dtv = bf2f(dt[base + (size_t)l * 1024]);
    const float zv = bf2f(lnz[base + (size_t)l * 1024]);
    const float a = 1.f / (1.f + __expf(dtv));
    const float zs = 1.f / (1.f + __expf(-zv));
    h = a * h + (1.f - a) * zs;
    h_out[base + (size_t)l * 1024] = h;
    hbf[base + (size_t)l * 1024] = f2bf(h);
  }
}

// ---------- 128x128 GEMM, 3 blocks/CU: C = A[M][K] @ B^T, B stored [N][K] bf16.
// TLP-maximized variant of the R12/R13 design: 4 waves (2Mx2N, wave tile
// 64x64, acc 64 AGPR), BK=64, ring of THREE 16 KiB halves (48 KiB LDS) ->
// 3 independent blocks/CU (144 KiB), 12 waves/CU as 3 separate dependency
// chains — cross-block MFMA covers each block's stage drain (m114).
// Halves: A(t) slot (2t)%3, B(t) slot (2t+1)%3 (advance +2/tile):
//  - stage A(t+1) -> slot (2t+2)%3 == B(t-1), dead since t-1 end barrier [ph0]
//  - stage B(t+1) -> slot (2t)%3 == A(t), after the post-MMAQ barrier
//  - vmcnt(0)+barrier at tile end -> t+1 resident (B stage latency exposed,
//    covered by the other 2 blocks' compute).
// 16x16x32 MFMA, conflict-free (row&7)<<4 XOR swizzle.
// EPI: 5 = fused3: bf16 outs {outH=dt, outH2=lnz, outH3=yg}, row stride 1024
//      2 = f32 out = (acc+b)*silu(gate bf16) + resid
//      6 = bf16 out = silu(acc+b)
//      7 = bf16 out = (acc+b)*bf2f(gate)   (gate may alias outH: in-place)
//      4 = f32 out = acc + b + outF (in-place residual add)
template <int EPI>
__global__ __launch_bounds__(256, 3) void gemm128(
    const u16* __restrict__ A, const u16* __restrict__ B,
    const float* __restrict__ bias, const u16* __restrict__ gate,
    const float* __restrict__ resid, float* __restrict__ outF,
    u16* __restrict__ outH, u16* __restrict__ outH2, u16* __restrict__ outH3,
    int ntx, int N, int K) {
  constexpr int SLOT = 16384;
  const int tid = threadIdx.x;
  const int lane = tid & 63;
  const int wid = tid >> 6;
  const int wrow = wid >> 1;   // 0..1 -> 64-row strip of the 128-row tile
  const int wcol = wid & 1;    // 0..1 -> 64-col strip of the 128-col tile

  // XCD-aware swizzle (grid %8==0 for all our launches)
  const int nwg = gridDim.x;
  int id = blockIdx.x;
  id = (id & 7) * (nwg >> 3) + (id >> 3);
  const int m0 = (id / ntx) * 128;
  const int n0 = (id % ntx) * 128;

  __shared__ __align__(16) char lds[3 * SLOT];

  f32x4 acc[4][4];   // [m-frag][n-frag] over the wave's 64x64 tile
#pragma unroll
  for (int m = 0; m < 4; ++m)
#pragma unroll
    for (int n = 0; n < 4; ++n) acc[m][n] = (f32x4){0.f, 0.f, 0.f, 0.f};

  bf16x8 aR[2];      // one m-frag (2 k) at a time
  bf16x8 bR[4][2];   // all 4 n-frags, held all tile

  // ---- hoisted LDS read offsets (m/n-frag at +2048, k=1 via ^64 —
  //      swizzle bits invariant under +16 rows; bit 6 disjoint) ----
  int aOff0, bOff0;
  {
    const int lq = (lane >> 4) << 4;
    const int ha = wrow * 64 + (lane & 15);
    aOff0 = ha * 128 + (lq ^ ((ha & 7) << 4));
    const int hb = wcol * 64 + (lane & 15);
    bOff0 = hb * 128 + (lq ^ ((hb & 7) << 4));
  }

  // ---- stage addressing: 256 thr x 16 B x 4 rounds = 16 KiB half.
  //      round i covers rows row0 + 32*i (row%8 invariant -> same swizzle) ----
  const int row0 = tid >> 3;                               // 0..31
  const int kb0  = ((tid & 7) * 16) ^ ((row0 & 7) << 4);   // inverse-swizzled src byte
  const size_t d32 = (size_t)64 * K;                       // +32 rows (bytes)
  const char* pA = (const char*)A + (size_t)(m0 + row0) * K * 2 + kb0;
  const char* pB = (const char*)B + (size_t)(n0 + row0) * K * 2 + kb0;
  const int ldst = tid * 16;                               // LDS offset within slot

#define STAGE(PTR, SB)                                                        \
  {                                                                           \
    gload_lds16(PTR, lds + (SB) + ldst);                                      \
    gload_lds16(PTR + d32, lds + (SB) + ldst + 4096);                         \
    gload_lds16(PTR + 2 * d32, lds + (SB) + ldst + 8192);                     \
    gload_lds16(PTR + 3 * d32, lds + (SB) + ldst + 12288);                    \
    PTR += 128;                                                               \
  }

#define READA(SAB, Q)                                                         \
  {                                                                           \
    const int _o = aOff0 + (Q) * 2048;                                        \
    aR[0] = *(const bf16x8*)(lds + (SAB) + _o);                               \
    aR[1] = *(const bf16x8*)(lds + (SAB) + (_o ^ 64));                        \
  }

#define READB(SBB)                                                            \
  _Pragma("unroll") for (int n = 0; n < 4; ++n) {                             \
    const int _o = bOff0 + n * 2048;                                          \
    bR[n][0] = *(const bf16x8*)(lds + (SBB) + _o);                            \
    bR[n][1] = *(const bf16x8*)(lds + (SBB) + (_o ^ 64));                     \
  }

#define MMAQ(Q)                                                               \
  __builtin_amdgcn_s_setprio(1);                                              \
  _Pragma("unroll") for (int n = 0; n < 4; ++n)                               \
  _Pragma("unroll") for (int k = 0; k < 2; ++k)                               \
      acc[Q][n] = __builtin_amdgcn_mfma_f32_16x16x32_bf16(                    \
          aR[k], bR[n][k], acc[Q][n], 0, 0, 0);                               \
  __builtin_amdgcn_s_setprio(0);

  const int NT = K >> 6;

  // prologue: A(0)->slot0, B(0)->slot1
  STAGE(pA, 0 * SLOT);
  STAGE(pB, 1 * SLOT);
  asm volatile("s_waitcnt vmcnt(0)" ::: "memory");
  __builtin_amdgcn_s_barrier();

  int sA = 0;   // slot of A(t) = (2t)%3; B(t) = sA+1 mod 3; A(t+1) = sA+2 mod 3

  for (int t = 0; t < NT; ++t) {
    int sB = sA + 1; if (sB >= 3) sB -= 3;
    int sN = sA + 2; if (sN >= 3) sN -= 3;   // A(t+1) target (dead B(t-1))
    const int sAb = __builtin_amdgcn_readfirstlane(sA * SLOT);
    const int sBb = __builtin_amdgcn_readfirstlane(sB * SLOT);
    const bool st = (t < NT - 1);
    // free-flowing: B burst + A bursts interleaved with MFMA
    READB(sBb);
    READA(sAb, 0);
    if (st) STAGE(pA, sN * SLOT);   // early: dead slot
    MMAQ(0);
    READA(sAb, 1); MMAQ(1);
    READA(sAb, 2); MMAQ(2);
    READA(sAb, 3); MMAQ(3);
    // barrier: all waves consumed A(t) and B(t)
    __builtin_amdgcn_s_barrier();
    if (st) STAGE(pB, sA * SLOT);   // B(t+1) -> old A(t) slot
    asm volatile("s_waitcnt vmcnt(0)" ::: "memory");
    __builtin_amdgcn_s_barrier();
    sA += 2; if (sA >= 3) sA -= 3;
  }

  // epilogue: C/D layout col = lane&15, row = (lane>>4)*4 + j
#pragma unroll
  for (int m = 0; m < 4; ++m) {
#pragma unroll
    for (int n = 0; n < 4; ++n) {
      const int col = n0 + wcol * 64 + n * 16 + (lane & 15);
#pragma unroll
      for (int j = 0; j < 4; ++j) {
        const int row = m0 + wrow * 64 + m * 16 + ((lane >> 4) << 2) + j;
        const float v = acc[m][n][j] + bias[col];
        if constexpr (EPI == 5) {
          const int rg = col >> 10;                     // block-uniform
          const size_t o = (size_t)row * 1024 + (col & 1023);
          if (rg == 0) outH[o] = f2bf(v);
          else if (rg == 1) outH2[o] = f2bf(v);
          else outH3[o] = f2bf(v);
        } else {
          const size_t o = (size_t)row * N + col;
          if constexpr (EPI == 2) {
            const float gt = bf2f(gate[o]);
            outF[o] = v * (gt / (1.f + __expf(-gt))) + resid[o];
          } else if constexpr (EPI == 6) {
            outH[o] = f2bf(v / (1.f + __expf(-v)));
          } else if constexpr (EPI == 7) {
            outH[o] = f2bf(v * bf2f(gate[o]));          // gate==outH ok (RAW per elem)
          } else if constexpr (EPI == 4) {
            outF[o] = v + outF[o];
          }
        }
      }
    }
  }
#undef STAGE
#undef READA
#undef READB
#undef MMAQ
}

extern "C" void kernel_launch(void* const* d_in, const int* in_sizes, int n_in,
                              void* d_out, int out_size, void* d_ws, size_t ws_size,
                              hipStream_t stream) {
  const float* x      = (const float*)d_in[0];
  const float* hidden = (const float*)d_in[1];
  const float* w_ln_z = (const float*)d_in[2];
  const float* b_ln_z = (const float*)d_in[3];
  const float* w_dt   = (const float*)d_in[4];
  const float* b_dt   = (const float*)d_in[5];
  const float* w_y    = (const float*)d_in[6];
  const float* b_y    = (const float*)d_in[7];
  const float* w_yg   = (const float*)d_in[8];
  const float* b_yg   = (const float*)d_in[9];
  const float* w_ff   = (const float*)d_in[10];
  const float* b_ff   = (const float*)d_in[11];
  const float* w_ffg  = (const float*)d_in[12];
  const float* b_ffg  = (const float*)d_in[13];
  const float* w_ffo  = (const float*)d_in[14];
  const float* b_ffo  = (const float*)d_in[15];
  const float* g_sio  = (const float*)d_in[16];
  const float* g_ffn  = (const float*)d_in[17];

  char* ws = (char*)d_ws;
  const size_t MB = 1ull << 20;
  u16*   WT_cat = (u16*)(ws + 0 * MB);      // 6 MiB  [3072][1024] (dt|lnz|yg)
  u16*   WT_y   = (u16*)(ws + 8 * MB);      // 2 MiB
  u16*   WT_ff  = (u16*)(ws + 10 * MB);     // 8 MiB  [4096][1024]
  u16*   WT_ffg = (u16*)(ws + 18 * MB);     // 8 MiB
  u16*   WT_ffo = (u16*)(ws + 26 * MB);     // 8 MiB  [1024][4096]
  float* b_cat  = (float*)(ws + 34 * MB);   // 12 KiB [3072]
  u16*   xn     = (u16*)(ws + 36 * MB);     // 32 MiB [16384][1024] bf16
  u16*   dt16   = (u16*)(ws + 68 * MB);     // 32 MiB bf16
  u16*   lnzb   = (u16*)(ws + 100 * MB);    // 32 MiB
  u16*   ygb    = (u16*)(ws + 132 * MB);    // 32 MiB
  u16*   hbf    = (u16*)(ws + 164 * MB);    // 32 MiB
  float* Pc     = (float*)(ws + 196 * MB);  // 1 MiB
  float* Sc     = (float*)(ws + 197 * MB);  // 1 MiB
  float* hin    = (float*)(ws + 198 * MB);  // 1 MiB
  u16*   gs     = (u16*)(ws + 68 * MB);     // 128 MiB overlay [16384][4096]
  // peak ws usage: 199 MiB

  float* x_out = (float*)d_out;
  float* h_out = (float*)d_out + (size_t)4 * 4096 * 1024;

  const int M = 16384, D = 1024, F = 4096;
  const dim3 tb(256);

  transpose_to_bf16<<<dim3(32, 32), tb, 0, stream>>>(w_dt, WT_cat, D, D);
  transpose_to_bf16<<<dim3(32, 32), tb, 0, stream>>>(w_ln_z, WT_cat + 1024 * 1024, D, D);
  transpose_to_bf16<<<dim3(32, 32), tb, 0, stream>>>(w_yg, WT_cat + 2 * 1024 * 1024, D, D);
  transpose_to_bf16<<<dim3(32, 32), tb, 0, stream>>>(w_y, WT_y, D, D);
  transpose_to_bf16<<<dim3(128, 32), tb, 0, stream>>>(w_ff, WT_ff, D, F);
  transpose_to_bf16<<<dim3(128, 32), tb, 0, stream>>>(w_ffg, WT_ffg, D, F);
  transpose_to_bf16<<<dim3(32, 128), tb, 0, stream>>>(w_ffo, WT_ffo, F, D);
  (void)hipMemcpyAsync(b_cat, b_dt, D * 4, hipMemcpyDeviceToDevice, stream);
  (void)hipMemcpyAsync(b_cat + 1024, b_ln_z, D * 4, hipMemcpyDeviceToDevice, stream);
  (void)hipMemcpyAsync(b_cat + 2048, b_yg, D * 4, hipMemcpyDeviceToDevice, stream);

  rmsnorm_kernel<<<M, tb, 0, stream>>>(x, g_sio, xn);

  // fused dt|lnz|yg GEMM: N=3072, ntx=24, grid 128*24
  gemm128<5><<<dim3(128 * 24), tb, 0, stream>>>(xn, WT_cat, b_cat, nullptr, nullptr,
                                                nullptr, dt16, lnzb, ygb, 24, 3072, D);

  scan_pass1<<<1024, tb, 0, stream>>>(dt16, lnzb, Pc, Sc);
  scan_pass2<<<16, tb, 0, stream>>>(Pc, Sc, hidden, hin);
  scan_pass3<<<1024, tb, 0, stream>>>(dt16, lnzb, hin, h_out, hbf);

  // x1 = (h@w_y + b_y) * silu(yg) + x   (N=1024, ntx=8, grid 128*8)
  gemm128<2><<<dim3(128 * 8), tb, 0, stream>>>(hbf, WT_y, b_y, ygb, x,
                                               x_out, nullptr, nullptr, nullptr, 8, D, D);

  rmsnorm_kernel<<<M, tb, 0, stream>>>(x_out, g_ffn, xn);

  // gs = silu(xn@w_ffg + b_ffg)   (N=4096, ntx=32, grid 128*32)
  gemm128<6><<<dim3(128 * 32), tb, 0, stream>>>(xn, WT_ffg, b_ffg, nullptr, nullptr,
                                                nullptr, gs, nullptr, nullptr, 32, F, D);
  // gs = (xn@w_ff + b_ff) * gs   (in-place gated mul)
  gemm128<7><<<dim3(128 * 32), tb, 0, stream>>>(xn, WT_ff, b_ff, gs, nullptr,
                                                nullptr, gs, nullptr, nullptr, 32, F, D);
  // x_out += gs@w_ffo + b_ffo   (N=1024, ntx=8, K=4096, grid 128*8)
  gemm128<4><<<dim3(128 * 8), tb, 0, stream>>>(gs, WT_ffo, b_ffo, nullptr, nullptr,
                                               x_out, nullptr, nullptr, nullptr, 8, D, F);
}

// Round 16
// 719.434 us; speedup vs baseline: 1.8502x; 1.1777x over previous
//
#include <hip/hip_runtime.h>
#include <cstdint>
#include <cstddef>

using u16 = unsigned short;
using bf16x8 = __attribute__((ext_vector_type(8))) short;
using f32x4  = __attribute__((ext_vector_type(4))) float;

__device__ __forceinline__ u16 f2bf(float f) {
  unsigned u = __float_as_uint(f);
  u += 0x7fffu + ((u >> 16) & 1u);
  return (u16)(u >> 16);
}
__device__ __forceinline__ float bf2f(u16 h) {
  return __uint_as_float(((unsigned)h) << 16);
}

__device__ __forceinline__ void gload_lds16(const void* g, void* l) {
  auto gp = reinterpret_cast<const __attribute__((address_space(1))) char*>(
      reinterpret_cast<uintptr_t>(g));
  auto lp = reinterpret_cast<__attribute__((address_space(3))) char*>(
      reinterpret_cast<uintptr_t>(l));
  __builtin_amdgcn_global_load_lds(gp, lp, 16, 0, 0);
}

// ---------- weight transpose + downcast: W f32[din][dout] -> WT bf16[dout][din]
__global__ __launch_bounds__(256) void transpose_to_bf16(
    const float* __restrict__ W, u16* __restrict__ WT, int din, int dout) {
  __shared__ float tile[32][33];
  const int j0 = blockIdx.x * 32;   // dout
  const int i0 = blockIdx.y * 32;   // din
  const int tx = threadIdx.x & 31;
  const int ty = threadIdx.x >> 5;  // 0..7
#pragma unroll
  for (int k = 0; k < 32; k += 8)
    tile[ty + k][tx] = W[(size_t)(i0 + ty + k) * dout + (j0 + tx)];
  __syncthreads();
#pragma unroll
  for (int k = 0; k < 32; k += 8)
    WT[(size_t)(j0 + ty + k) * din + (i0 + tx)] = f2bf(tile[tx][ty + k]);
}

// ---------- rmsnorm f32 -> bf16, one block per row of 1024
__global__ __launch_bounds__(256) void rmsnorm_kernel(
    const float* __restrict__ x, const float* __restrict__ g, u16* __restrict__ xn) {
  const int row = blockIdx.x;
  const float4 v = ((const float4*)(x + (size_t)row * 1024))[threadIdx.x];
  float ss = v.x * v.x + v.y * v.y + v.z * v.z + v.w * v.w;
#pragma unroll
  for (int off = 32; off > 0; off >>= 1) ss += __shfl_down(ss, off, 64);
  __shared__ float red[4];
  if ((threadIdx.x & 63) == 0) red[threadIdx.x >> 6] = ss;
  __syncthreads();
  const float rs = rsqrtf((red[0] + red[1] + red[2] + red[3]) * (1.f / 1024.f) + 1e-6f);
  const float4 gv = ((const float4*)g)[threadIdx.x];
  ushort4 o;
  o.x = f2bf(v.x * rs * gv.x);
  o.y = f2bf(v.y * rs * gv.y);
  o.z = f2bf(v.z * rs * gv.z);
  o.w = f2bf(v.w * rs * gv.w);
  ((ushort4*)(xn + (size_t)row * 1024))[threadIdx.x] = o;
}

// ---------- chunked linear-recurrence scan: h[l] = sig(-dt)*h[l-1] + sig(dt)*sig(lnz)
__global__ __launch_bounds__(256) void scan_pass1(
    const u16* __restrict__ dt, const u16* __restrict__ lnz,
    float* __restrict__ P, float* __restrict__ S) {
  const int blk = blockIdx.x;              // B*64*4 = 1024 blocks
  const int dblk = blk & 3;
  const int chunk = (blk >> 2) & 63;
  const int b = blk >> 8;
  const int d = dblk * 256 + threadIdx.x;
  const size_t base = ((size_t)b * 4096 + (size_t)chunk * 64) * 1024 + d;
  float p = 1.f, s = 0.f;
#pragma unroll 8
  for (int l = 0; l < 64; ++l) {
    const float dtv = bf2f(dt[base + (size_t)l * 1024]);
    const float zv = bf2f(lnz[base + (size_t)l * 1024]);
    const float a = 1.f / (1.f + __expf(dtv));        // sigmoid(-dt)
    const float zs = 1.f / (1.f + __expf(-zv));       // sigmoid(lnz_pre)
    const float in = (1.f - a) * zs;
    p *= a;
    s = a * s + in;
  }
  const size_t o = ((size_t)b * 64 + chunk) * 1024 + d;
  P[o] = p;
  S[o] = s;
}

__global__ __launch_bounds__(256) void scan_pass2(
    const float* __restrict__ P, const float* __restrict__ S,
    const float* __restrict__ hidden, float* __restrict__ hin) {
  const int idx = blockIdx.x * 256 + threadIdx.x;  // 0..4095
  const int b = idx >> 10, d = idx & 1023;
  float h = hidden[idx];
#pragma unroll 8
  for (int c = 0; c < 64; ++c) {
    const size_t o = ((size_t)b * 64 + c) * 1024 + d;
    hin[o] = h;
    h = P[o] * h + S[o];
  }
}

__global__ __launch_bounds__(256) void scan_pass3(
    const u16* __restrict__ dt, const u16* __restrict__ lnz,
    const float* __restrict__ hin, float* __restrict__ h_out, u16* __restrict__ hbf) {
  const int blk = blockIdx.x;
  const int dblk = blk & 3;
  const int chunk = (blk >> 2) & 63;
  const int b = blk >> 8;
  const int d = dblk * 256 + threadIdx.x;
  const size_t base = ((size_t)b * 4096 + (size_t)chunk * 64) * 1024 + d;
  float h = hin[((size_t)b * 64 + chunk) * 1024 + d];
#pragma unroll 4
  for (int l = 0; l < 64; ++l) {
    const float dtv = bf2f(dt[base + (size_t)l * 1024]);
    const float zv = bf2f(lnz[base + (size_t)l * 1024]);
    const float a = 1.f / (1.f + __expf(dtv));
    const float zs = 1.f / (1.f + __expf(-zv));
    h = a * h + (1.f - a) * zs;
    h_out[base + (size_t)l * 1024] = h;
    hbf[base + (size_t)l * 1024] = f2bf(h);
  }
}

// ---------- 256x128 GEMM (R13 keeper), 2 blocks/CU, 4Mx2N waves.
// EPI: 5 = fused3: bf16 outs {outH=dt, outH2=lnz, outH3=yg}, row stride 1024
//      2 = f32 out = (acc+b)*silu(gate bf16) + resid
//      4 = f32 out = acc + b + outF (in-place residual add)
template <int EPI>
__global__ __launch_bounds__(512, 4) void gemm256(
    const u16* __restrict__ A, const u16* __restrict__ B,
    const float* __restrict__ bias, const u16* __restrict__ gate,
    const float* __restrict__ resid, float* __restrict__ outF,
    u16* __restrict__ outH, u16* __restrict__ outH2, u16* __restrict__ outH3,
    int ntx, int N, int K) {
  constexpr int SLOT = 16384;
  const int tid = threadIdx.x;
  const int lane = tid & 63;
  const int wid = tid >> 6;
  const int wrow = wid >> 1;   // 0..3 -> 64-row strip
  const int wcol = wid & 1;    // 0..1 -> 64-col strip
  const int whalf = wrow >> 1;
  const int wsub  = wrow & 1;

  const int nwg = gridDim.x;
  int id = blockIdx.x;
  id = (id & 7) * (nwg >> 3) + (id >> 3);
  const int m0 = (id / ntx) * 256;
  const int n0 = (id % ntx) * 128;

  __shared__ __align__(16) char lds[5 * SLOT];

  f32x4 acc[4][4];
#pragma unroll
  for (int m = 0; m < 4; ++m)
#pragma unroll
    for (int n = 0; n < 4; ++n) acc[m][n] = (f32x4){0.f, 0.f, 0.f, 0.f};

  bf16x8 aR[2];
  bf16x8 bR[4][2];

  int aOff0, bOff0;
  {
    const int lq = (lane >> 4) << 4;
    const int ha = wsub * 64 + (lane & 15);
    aOff0 = ha * 128 + (lq ^ ((ha & 7) << 4));
    const int hb = wcol * 64 + (lane & 15);
    bOff0 = hb * 128 + (lq ^ ((hb & 7) << 4));
  }

  const int row0 = tid >> 3;
  const int kb0  = ((tid & 7) * 16) ^ ((row0 & 7) << 4);
  const size_t dRow = (size_t)128 * K;
  const char* pA0 = (const char*)A + (size_t)(m0 + row0) * K * 2 + kb0;
  const char* pA1 = pA0 + (size_t)256 * K;
  const char* pB  = (const char*)B + (size_t)(n0 + row0) * K * 2 + kb0;
  const int ldst = tid * 16;

#define STAGE(PTR, SB)                                                        \
  {                                                                           \
    gload_lds16(PTR, lds + (SB) + ldst);                                      \
    gload_lds16(PTR + dRow, lds + (SB) + ldst + 8192);                        \
    PTR += 128;                                                               \
  }

#define READA(SAB, Q)                                                         \
  {                                                                           \
    const int _o = aOff0 + (Q) * 2048;                                        \
    aR[0] = *(const bf16x8*)(lds + (SAB) + _o);                               \
    aR[1] = *(const bf16x8*)(lds + (SAB) + (_o ^ 64));                        \
  }

#define READB(SBB)                                                            \
  _Pragma("unroll") for (int n = 0; n < 4; ++n) {                             \
    const int _o = bOff0 + n * 2048;                                          \
    bR[n][0] = *(const bf16x8*)(lds + (SBB) + _o);                            \
    bR[n][1] = *(const bf16x8*)(lds + (SBB) + (_o ^ 64));                     \
  }

#define MMAQ(Q)                                                               \
  __builtin_amdgcn_s_setprio(1);                                              \
  _Pragma("unroll") for (int n = 0; n < 4; ++n)                               \
  _Pragma("unroll") for (int k = 0; k < 2; ++k)                               \
      acc[Q][n] = __builtin_amdgcn_mfma_f32_16x16x32_bf16(                    \
          aR[k], bR[n][k], acc[Q][n], 0, 0, 0);                               \
  __builtin_amdgcn_s_setprio(0);

  const int NT = K >> 6;

  STAGE(pB,  0 * SLOT);
  STAGE(pA0, 1 * SLOT);
  STAGE(pA1, 2 * SLOT);
  asm volatile("s_waitcnt vmcnt(0)" ::: "memory");
  __builtin_amdgcn_s_barrier();

  int iB = 0;

  for (int t = 0; t < NT; ++t) {
    int ib1 = iB + 1 + whalf; if (ib1 >= 5) ib1 -= 5;
    const int sAb = __builtin_amdgcn_readfirstlane(ib1 * SLOT);
    const int sBb = __builtin_amdgcn_readfirstlane(iB * SLOT);
    int i0s = iB + 3; if (i0s >= 5) i0s -= 5;
    int i1s = iB + 4; if (i1s >= 5) i1s -= 5;
    const int s0 = i0s * SLOT, s1 = i1s * SLOT, s2 = iB * SLOT;
    const bool st = (t < NT - 1);
    READB(sBb);
    READA(sAb, 0);
    if (st) STAGE(pB, s0);
    MMAQ(0);
    READA(sAb, 1);
    if (st) STAGE(pA0, s1);
    MMAQ(1);
    READA(sAb, 2);
    MMAQ(2);
    __builtin_amdgcn_s_barrier();
    READA(sAb, 3);
    if (st) STAGE(pA1, s2);
    MMAQ(3);
    asm volatile("s_waitcnt vmcnt(0)" ::: "memory");
    __builtin_amdgcn_s_barrier();
    iB += 3; if (iB >= 5) iB -= 5;
  }

#pragma unroll
  for (int m = 0; m < 4; ++m) {
#pragma unroll
    for (int n = 0; n < 4; ++n) {
      const int col = n0 + wcol * 64 + n * 16 + (lane & 15);
#pragma unroll
      for (int j = 0; j < 4; ++j) {
        const int row = m0 + wrow * 64 + m * 16 + ((lane >> 4) << 2) + j;
        const float v = acc[m][n][j] + bias[col];
        if constexpr (EPI == 5) {
          const int rg = col >> 10;
          const size_t o = (size_t)row * 1024 + (col & 1023);
          if (rg == 0) outH[o] = f2bf(v);
          else if (rg == 1) outH2[o] = f2bf(v);
          else outH3[o] = f2bf(v);
        } else {
          const size_t o = (size_t)row * N + col;
          if constexpr (EPI == 2) {
            const float gt = bf2f(gate[o]);
            outF[o] = v * (gt / (1.f + __expf(-gt))) + resid[o];
          } else if constexpr (EPI == 4) {
            outF[o] = v + outF[o];
          }
        }
      }
    }
  }
#undef STAGE
#undef READA
#undef READB
#undef MMAQ
}

// ---------- DUAL 256x64 GEMM: gs = (A@B1^T + b1) * silu(A@B2^T + b2), bf16 out.
// R13 structure verbatim: 2 blocks/CU (80 KiB ring-5, acc 64 AGPR), halves
// per tile {Bpair 16K (B1 panel @+0, B2 panel @+8192), A0 16K, A1 16K},
// advance +3 mod 5, same slot audit as R13. 8 waves 4Mx2N; wave tile 64x32
// of the FINAL output, both accumulators live (acc1+acc2 = 64 f32).
// Eliminates the gs intermediate round-trip (384 MB -> 128 MB EPI traffic)
// and stages A once for both GEMMs.
__global__ __launch_bounds__(512, 4) void gemm_dual(
    const u16* __restrict__ A, const u16* __restrict__ B1, const u16* __restrict__ B2,
    const float* __restrict__ bias1, const float* __restrict__ bias2,
    u16* __restrict__ outH, int ntx, int N, int K) {
  constexpr int SLOT = 16384;
  const int tid = threadIdx.x;
  const int lane = tid & 63;
  const int wid = tid >> 6;
  const int wrow = wid >> 1;   // 0..3 -> 64-row strip of 256
  const int wcol = wid & 1;    // 0..1 -> 32-col strip of 64
  const int whalf = wrow >> 1;
  const int wsub  = wrow & 1;

  const int nwg = gridDim.x;
  int id = blockIdx.x;
  id = (id & 7) * (nwg >> 3) + (id >> 3);
  const int m0 = (id / ntx) * 256;
  const int n0 = (id % ntx) * 64;

  __shared__ __align__(16) char lds[5 * SLOT];

  f32x4 acc1[4][2], acc2[4][2];
#pragma unroll
  for (int m = 0; m < 4; ++m)
#pragma unroll
    for (int n = 0; n < 2; ++n) {
      acc1[m][n] = (f32x4){0.f, 0.f, 0.f, 0.f};
      acc2[m][n] = (f32x4){0.f, 0.f, 0.f, 0.f};
    }

  bf16x8 aR[2];
  bf16x8 b1R[2][2], b2R[2][2];

  int aOff0, bOff0;
  {
    const int lq = (lane >> 4) << 4;
    const int ha = wsub * 64 + (lane & 15);
    aOff0 = ha * 128 + (lq ^ ((ha & 7) << 4));
    const int hb = wcol * 32 + (lane & 15);      // B panel is 64 rows x 128 B
    bOff0 = hb * 128 + (lq ^ ((hb & 7) << 4));
  }

  const int row0 = tid >> 3;                     // 0..63
  const int kb0  = ((tid & 7) * 16) ^ ((row0 & 7) << 4);
  const size_t dRow = (size_t)128 * K;
  const char* pA0 = (const char*)A + (size_t)(m0 + row0) * K * 2 + kb0;
  const char* pA1 = pA0 + (size_t)256 * K;
  const char* pB1 = (const char*)B1 + (size_t)(n0 + row0) * K * 2 + kb0;
  const char* pB2 = (const char*)B2 + (size_t)(n0 + row0) * K * 2 + kb0;
  const int ldst = tid * 16;                     // 512 thr x 16 B = 8 KiB round

#define STAGEA(PTR, SB)                                                       \
  {                                                                           \
    gload_lds16(PTR, lds + (SB) + ldst);                                      \
    gload_lds16(PTR + dRow, lds + (SB) + ldst + 8192);                        \
    PTR += 128;                                                               \
  }
#define STAGEB(PTR, SB, OFF)                                                  \
  {                                                                           \
    gload_lds16(PTR, lds + (SB) + (OFF) + ldst);                              \
    PTR += 128;                                                               \
  }

#define READA(SAB, Q)                                                         \
  {                                                                           \
    const int _o = aOff0 + (Q) * 2048;                                        \
    aR[0] = *(const bf16x8*)(lds + (SAB) + _o);                               \
    aR[1] = *(const bf16x8*)(lds + (SAB) + (_o ^ 64));                        \
  }

#define READBD(SBB)                                                           \
  _Pragma("unroll") for (int n = 0; n < 2; ++n) {                             \
    const int _o = bOff0 + n * 2048;                                          \
    b1R[n][0] = *(const bf16x8*)(lds + (SBB) + _o);                           \
    b1R[n][1] = *(const bf16x8*)(lds + (SBB) + (_o ^ 64));                    \
    b2R[n][0] = *(const bf16x8*)(lds + (SBB) + 8192 + _o);                    \
    b2R[n][1] = *(const bf16x8*)(lds + (SBB) + 8192 + (_o ^ 64));             \
  }

#define MMAD(Q)                                                               \
  __builtin_amdgcn_s_setprio(1);                                              \
  _Pragma("unroll") for (int n = 0; n < 2; ++n)                               \
  _Pragma("unroll") for (int k = 0; k < 2; ++k) {                             \
    acc1[Q][n] = __builtin_amdgcn_mfma_f32_16x16x32_bf16(                     \
        aR[k], b1R[n][k], acc1[Q][n], 0, 0, 0);                               \
    acc2[Q][n] = __builtin_amdgcn_mfma_f32_16x16x32_bf16(                     \
        aR[k], b2R[n][k], acc2[Q][n], 0, 0, 0);                               \
  }                                                                           \
  __builtin_amdgcn_s_setprio(0);

  const int NT = K >> 6;

  // prologue: Bpair(0)->slot0, A0(0)->slot1, A1(0)->slot2
  STAGEB(pB1, 0 * SLOT, 0);
  STAGEB(pB2, 0 * SLOT, 8192);
  STAGEA(pA0, 1 * SLOT);
  STAGEA(pA1, 2 * SLOT);
  asm volatile("s_waitcnt vmcnt(0)" ::: "memory");
  __builtin_amdgcn_s_barrier();

  int iB = 0;   // slot of tile t's Bpair; A0 at iB+1, A1 at iB+2; advance +3

  for (int t = 0; t < NT; ++t) {
    int ib1 = iB + 1 + whalf; if (ib1 >= 5) ib1 -= 5;
    const int sAb = __builtin_amdgcn_readfirstlane(ib1 * SLOT);
    const int sBb = __builtin_amdgcn_readfirstlane(iB * SLOT);
    int i0s = iB + 3; if (i0s >= 5) i0s -= 5;    // Bpair(t+1) -> dead slot
    int i1s = iB + 4; if (i1s >= 5) i1s -= 5;    // A0(t+1)    -> dead slot
    const int s0 = i0s * SLOT, s1 = i1s * SLOT, s2 = iB * SLOT;  // A1(t+1)
    const bool st = (t < NT - 1);
    READBD(sBb);
    READA(sAb, 0);
    if (st) {
      STAGEB(pB1, s0, 0);
      STAGEB(pB2, s0, 8192);
    }
    MMAD(0);
    READA(sAb, 1);
    if (st) STAGEA(pA0, s1);
    MMAD(1);
    READA(sAb, 2);
    MMAD(2);
    // mid barrier: Bpair reads (ph0) + A reads so far complete before s2 reuse
    __builtin_amdgcn_s_barrier();
    READA(sAb, 3);
    if (st) STAGEA(pA1, s2);
    MMAD(3);
    asm volatile("s_waitcnt vmcnt(0)" ::: "memory");
    __builtin_amdgcn_s_barrier();
    iB += 3; if (iB >= 5) iB -= 5;
  }

  // epilogue: gs = (acc1+b1) * silu(acc2+b2), bf16
#pragma unroll
  for (int m = 0; m < 4; ++m) {
#pragma unroll
    for (int n = 0; n < 2; ++n) {
      const int col = n0 + wcol * 32 + n * 16 + (lane & 15);
#pragma unroll
      for (int j = 0; j < 4; ++j) {
        const int row = m0 + wrow * 64 + m * 16 + ((lane >> 4) << 2) + j;
        const float v1 = acc1[m][n][j] + bias1[col];
        const float v2 = acc2[m][n][j] + bias2[col];
        outH[(size_t)row * N + col] = f2bf(v1 * (v2 / (1.f + __expf(-v2))));
      }
    }
  }
#undef STAGEA
#undef STAGEB
#undef READA
#undef READBD
#undef MMAD
}

extern "C" void kernel_launch(void* const* d_in, const int* in_sizes, int n_in,
                              void* d_out, int out_size, void* d_ws, size_t ws_size,
                              hipStream_t stream) {
  const float* x      = (const float*)d_in[0];
  const float* hidden = (const float*)d_in[1];
  const float* w_ln_z = (const float*)d_in[2];
  const float* b_ln_z = (const float*)d_in[3];
  const float* w_dt   = (const float*)d_in[4];
  const float* b_dt   = (const float*)d_in[5];
  const float* w_y    = (const float*)d_in[6];
  const float* b_y    = (const float*)d_in[7];
  const float* w_yg   = (const float*)d_in[8];
  const float* b_yg   = (const float*)d_in[9];
  const float* w_ff   = (const float*)d_in[10];
  const float* b_ff   = (const float*)d_in[11];
  const float* w_ffg  = (const float*)d_in[12];
  const float* b_ffg  = (const float*)d_in[13];
  const float* w_ffo  = (const float*)d_in[14];
  const float* b_ffo  = (const float*)d_in[15];
  const float* g_sio  = (const float*)d_in[16];
  const float* g_ffn  = (const float*)d_in[17];

  char* ws = (char*)d_ws;
  const size_t MB = 1ull << 20;
  u16*   WT_cat = (u16*)(ws + 0 * MB);      // 6 MiB  [3072][1024] (dt|lnz|yg)
  u16*   WT_y   = (u16*)(ws + 8 * MB);      // 2 MiB
  u16*   WT_ff  = (u16*)(ws + 10 * MB);     // 8 MiB  [4096][1024]
  u16*   WT_ffg = (u16*)(ws + 18 * MB);     // 8 MiB
  u16*   WT_ffo = (u16*)(ws + 26 * MB);     // 8 MiB  [1024][4096]
  float* b_cat  = (float*)(ws + 34 * MB);   // 12 KiB [3072]
  u16*   xn     = (u16*)(ws + 36 * MB);     // 32 MiB [16384][1024] bf16
  u16*   dt16   = (u16*)(ws + 68 * MB);     // 32 MiB bf16
  u16*   lnzb   = (u16*)(ws + 100 * MB);    // 32 MiB
  u16*   ygb    = (u16*)(ws + 132 * MB);    // 32 MiB
  u16*   hbf    = (u16*)(ws + 164 * MB);    // 32 MiB
  float* Pc     = (float*)(ws + 196 * MB);  // 1 MiB
  float* Sc     = (float*)(ws + 197 * MB);  // 1 MiB
  float* hin    = (float*)(ws + 198 * MB);  // 1 MiB
  u16*   gs     = (u16*)(ws + 68 * MB);     // 128 MiB overlay [16384][4096]
  // peak ws usage: 199 MiB

  float* x_out = (float*)d_out;
  float* h_out = (float*)d_out + (size_t)4 * 4096 * 1024;

  const int M = 16384, D = 1024, F = 4096;
  const dim3 tb(256);

  transpose_to_bf16<<<dim3(32, 32), tb, 0, stream>>>(w_dt, WT_cat, D, D);
  transpose_to_bf16<<<dim3(32, 32), tb, 0, stream>>>(w_ln_z, WT_cat + 1024 * 1024, D, D);
  transpose_to_bf16<<<dim3(32, 32), tb, 0, stream>>>(w_yg, WT_cat + 2 * 1024 * 1024, D, D);
  transpose_to_bf16<<<dim3(32, 32), tb, 0, stream>>>(w_y, WT_y, D, D);
  transpose_to_bf16<<<dim3(128, 32), tb, 0, stream>>>(w_ff, WT_ff, D, F);
  transpose_to_bf16<<<dim3(128, 32), tb, 0, stream>>>(w_ffg, WT_ffg, D, F);
  transpose_to_bf16<<<dim3(32, 128), tb, 0, stream>>>(w_ffo, WT_ffo, F, D);
  (void)hipMemcpyAsync(b_cat, b_dt, D * 4, hipMemcpyDeviceToDevice, stream);
  (void)hipMemcpyAsync(b_cat + 1024, b_ln_z, D * 4, hipMemcpyDeviceToDevice, stream);
  (void)hipMemcpyAsync(b_cat + 2048, b_yg, D * 4, hipMemcpyDeviceToDevice, stream);

  rmsnorm_kernel<<<M, tb, 0, stream>>>(x, g_sio, xn);

  // fused dt|lnz|yg GEMM: N=3072, ntx=24
  gemm256<5><<<dim3(64 * 24), 512, 0, stream>>>(xn, WT_cat, b_cat, nullptr, nullptr,
                                                nullptr, dt16, lnzb, ygb, 24, 3072, D);

  scan_pass1<<<1024, tb, 0, stream>>>(dt16, lnzb, Pc, Sc);
  scan_pass2<<<16, tb, 0, stream>>>(Pc, Sc, hidden, hin);
  scan_pass3<<<1024, tb, 0, stream>>>(dt16, lnzb, hin, h_out, hbf);

  // x1 = (h@w_y + b_y) * silu(yg) + x   (N=1024, ntx=8)
  gemm256<2><<<dim3(64 * 8), 512, 0, stream>>>(hbf, WT_y, b_y, ygb, x,
                                               x_out, nullptr, nullptr, nullptr, 8, D, D);

  rmsnorm_kernel<<<M, tb, 0, stream>>>(x_out, g_ffn, xn);

  // gs = (xn@w_ff + b_ff) * silu(xn@w_ffg + b_ffg)   [DUAL, N=4096, ntx=64]
  gemm_dual<<<dim3(64 * 64), 512, 0, stream>>>(xn, WT_ff, WT_ffg, b_ff, b_ffg,
                                               gs, 64, F, D);

  // x_out += gs@w_ffo + b_ffo   (N=1024, ntx=8, K=4096)
  gemm256<4><<<dim3(64 * 8), 512, 0, stream>>>(gs, WT_ffo, b_ffo, nullptr, nullptr,
                                               x_out, nullptr, nullptr, nullptr, 8, D, F);
}

// Round 17
// 716.844 us; speedup vs baseline: 1.8569x; 1.0036x over previous
//
#include <hip/hip_runtime.h>
#include <cstdint>
#include <cstddef>

using u16 = unsigned short;
using bf16x8 = __attribute__((ext_vector_type(8))) short;
using f32x4  = __attribute__((ext_vector_type(4))) float;

__device__ __forceinline__ u16 f2bf(float f) {
  unsigned u = __float_as_uint(f);
  u += 0x7fffu + ((u >> 16) & 1u);
  return (u16)(u >> 16);
}
__device__ __forceinline__ float bf2f(u16 h) {
  return __uint_as_float(((unsigned)h) << 16);
}

__device__ __forceinline__ void gload_lds16(const void* g, void* l) {
  auto gp = reinterpret_cast<const __attribute__((address_space(1))) char*>(
      reinterpret_cast<uintptr_t>(g));
  auto lp = reinterpret_cast<__attribute__((address_space(3))) char*>(
      reinterpret_cast<uintptr_t>(l));
  __builtin_amdgcn_global_load_lds(gp, lp, 16, 0, 0);
}

// ---------- weight transpose + downcast: W f32[din][dout] -> WT bf16[dout][din]
__global__ __launch_bounds__(256) void transpose_to_bf16(
    const float* __restrict__ W, u16* __restrict__ WT, int din, int dout) {
  __shared__ float tile[32][33];
  const int j0 = blockIdx.x * 32;   // dout
  const int i0 = blockIdx.y * 32;   // din
  const int tx = threadIdx.x & 31;
  const int ty = threadIdx.x >> 5;  // 0..7
#pragma unroll
  for (int k = 0; k < 32; k += 8)
    tile[ty + k][tx] = W[(size_t)(i0 + ty + k) * dout + (j0 + tx)];
  __syncthreads();
#pragma unroll
  for (int k = 0; k < 32; k += 8)
    WT[(size_t)(j0 + ty + k) * din + (i0 + tx)] = f2bf(tile[tx][ty + k]);
}

// ---------- rmsnorm f32 -> bf16, one block per row of 1024
__global__ __launch_bounds__(256) void rmsnorm_kernel(
    const float* __restrict__ x, const float* __restrict__ g, u16* __restrict__ xn) {
  const int row = blockIdx.x;
  const float4 v = ((const float4*)(x + (size_t)row * 1024))[threadIdx.x];
  float ss = v.x * v.x + v.y * v.y + v.z * v.z + v.w * v.w;
#pragma unroll
  for (int off = 32; off > 0; off >>= 1) ss += __shfl_down(ss, off, 64);
  __shared__ float red[4];
  if ((threadIdx.x & 63) == 0) red[threadIdx.x >> 6] = ss;
  __syncthreads();
  const float rs = rsqrtf((red[0] + red[1] + red[2] + red[3]) * (1.f / 1024.f) + 1e-6f);
  const float4 gv = ((const float4*)g)[threadIdx.x];
  ushort4 o;
  o.x = f2bf(v.x * rs * gv.x);
  o.y = f2bf(v.y * rs * gv.y);
  o.z = f2bf(v.z * rs * gv.z);
  o.w = f2bf(v.w * rs * gv.w);
  ((ushort4*)(xn + (size_t)row * 1024))[threadIdx.x] = o;
}

// ---------- chunked linear-recurrence scan: h[l] = sig(-dt)*h[l-1] + sig(dt)*sig(lnz)
__global__ __launch_bounds__(256) void scan_pass1(
    const u16* __restrict__ dt, const u16* __restrict__ lnz,
    float* __restrict__ P, float* __restrict__ S) {
  const int blk = blockIdx.x;              // B*64*4 = 1024 blocks
  const int dblk = blk & 3;
  const int chunk = (blk >> 2) & 63;
  const int b = blk >> 8;
  const int d = dblk * 256 + threadIdx.x;
  const size_t base = ((size_t)b * 4096 + (size_t)chunk * 64) * 1024 + d;
  float p = 1.f, s = 0.f;
#pragma unroll 8
  for (int l = 0; l < 64; ++l) {
    const float dtv = bf2f(dt[base + (size_t)l * 1024]);
    const float zv = bf2f(lnz[base + (size_t)l * 1024]);
    const float a = 1.f / (1.f + __expf(dtv));        // sigmoid(-dt)
    const float zs = 1.f / (1.f + __expf(-zv));       // sigmoid(lnz_pre)
    const float in = (1.f - a) * zs;
    p *= a;
    s = a * s + in;
  }
  const size_t o = ((size_t)b * 64 + chunk) * 1024 + d;
  P[o] = p;
  S[o] = s;
}

__global__ __launch_bounds__(256) void scan_pass2(
    const float* __restrict__ P, const float* __restrict__ S,
    const float* __restrict__ hidden, float* __restrict__ hin) {
  const int idx = blockIdx.x * 256 + threadIdx.x;  // 0..4095
  const int b = idx >> 10, d = idx & 1023;
  float h = hidden[idx];
#pragma unroll 8
  for (int c = 0; c < 64; ++c) {
    const size_t o = ((size_t)b * 64 + c) * 1024 + d;
    hin[o] = h;
    h = P[o] * h + S[o];
  }
}

__global__ __launch_bounds__(256) void scan_pass3(
    const u16* __restrict__ dt, const u16* __restrict__ lnz,
    const float* __restrict__ hin, float* __restrict__ h_out, u16* __restrict__ hbf) {
  const int blk = blockIdx.x;
  const int dblk = blk & 3;
  const int chunk = (blk >> 2) & 63;
  const int b = blk >> 8;
  const int d = dblk * 256 + threadIdx.x;
  const size_t base = ((size_t)b * 4096 + (size_t)chunk * 64) * 1024 + d;
  float h = hin[((size_t)b * 64 + chunk) * 1024 + d];
#pragma unroll 4
  for (int l = 0; l < 64; ++l) {
    const float dtv = bf2f(dt[base + (size_t)l * 1024]);
    const float zv = bf2f(lnz[base + (size_t)l * 1024]);
    const float a = 1.f / (1.f + __expf(dtv));
    const float zs = 1.f / (1.f + __expf(-zv));
    h = a * h + (1.f - a) * zs;
    h_out[base + (size_t)l * 1024] = h;
    hbf[base + (size_t)l * 1024] = f2bf(h);
  }
}

// ---------- PAIR GEMM (R16 dual structure, generalized): 2 blocks/CU,
// 8 waves 4Mx2N, 80 KiB ring-5, acc1+acc2 = 64 AGPR (two INDEPENDENT
// accumulator chains per aR fragment — the dual's 47.6%-MfmaUtil mechanism).
// Halves per tile: {Bpair 16K (B1 panel @+0, B2 panel @+8192), A0, A1};
// ring advances +3 mod 5 (slot audit = R13/R16).
// Modes:
//  EPI==3 (gated dual): B1,B2 = distinct matrices, SAME 64 output cols;
//    out = f2bf((acc1+biasA[col]) * silu(acc2+biasB[col])); block covers
//    64 cols (n0 = tile*64).
//  else (pair): B2 = B1 + 64 rows; acc1 -> cols [n0,n0+64), acc2 ->
//    [n0+64,n0+128); block covers 128 cols (n0 = tile*128); bias = biasA[col].
//  EPI 5 = fused3 bf16 triple-split (row stride 1024)
//  EPI 2 = f32 out = (acc+b)*silu(gate bf16) + resid
//  EPI 4 = f32 out = acc + b + outF (in-place residual add)
template <int EPI>
__global__ __launch_bounds__(512, 4) void gemm_pair(
    const u16* __restrict__ A, const u16* __restrict__ B1, const u16* __restrict__ B2,
    const float* __restrict__ biasA, const float* __restrict__ biasB,
    const u16* __restrict__ gate, const float* __restrict__ resid,
    float* __restrict__ outF, u16* __restrict__ outH,
    u16* __restrict__ outH2, u16* __restrict__ outH3,
    int ntx, int N, int K) {
  constexpr int SLOT = 16384;
  constexpr bool GATED = (EPI == 3);
  const int tid = threadIdx.x;
  const int lane = tid & 63;
  const int wid = tid >> 6;
  const int wrow = wid >> 1;   // 0..3 -> 64-row strip of 256
  const int wcol = wid & 1;    // 0..1 -> 32-col strip of the 64-col panel
  const int whalf = wrow >> 1;
  const int wsub  = wrow & 1;

  // XCD-aware swizzle (grid %8==0 for all our launches)
  const int nwg = gridDim.x;
  int id = blockIdx.x;
  id = (id & 7) * (nwg >> 3) + (id >> 3);
  const int m0 = (id / ntx) * 256;
  const int n0 = (id % ntx) * (GATED ? 64 : 128);

  __shared__ __align__(16) char lds[5 * SLOT];

  f32x4 acc1[4][2], acc2[4][2];
#pragma unroll
  for (int m = 0; m < 4; ++m)
#pragma unroll
    for (int n = 0; n < 2; ++n) {
      acc1[m][n] = (f32x4){0.f, 0.f, 0.f, 0.f};
      acc2[m][n] = (f32x4){0.f, 0.f, 0.f, 0.f};
    }

  bf16x8 aR[2];
  bf16x8 b1R[2][2], b2R[2][2];

  int aOff0, bOff0;
  {
    const int lq = (lane >> 4) << 4;
    const int ha = wsub * 64 + (lane & 15);
    aOff0 = ha * 128 + (lq ^ ((ha & 7) << 4));
    const int hb = wcol * 32 + (lane & 15);      // B panel: 64 rows x 128 B
    bOff0 = hb * 128 + (lq ^ ((hb & 7) << 4));
  }

  const int row0 = tid >> 3;                     // 0..63
  const int kb0  = ((tid & 7) * 16) ^ ((row0 & 7) << 4);
  const size_t dRow = (size_t)128 * K;
  const char* pA0 = (const char*)A + (size_t)(m0 + row0) * K * 2 + kb0;
  const char* pA1 = pA0 + (size_t)256 * K;
  const char* pB1 = (const char*)B1 + (size_t)(n0 + row0) * K * 2 + kb0;
  // pair mode: B2 strip = rows n0+64.. of the SAME matrix (caller passes B2=B1)
  const char* pB2 = (const char*)B2 +
                    (size_t)((GATED ? n0 : n0 + 64) + row0) * K * 2 + kb0;
  const int ldst = tid * 16;                     // 512 thr x 16 B = 8 KiB round

#define STAGEA(PTR, SB)                                                       \
  {                                                                           \
    gload_lds16(PTR, lds + (SB) + ldst);                                      \
    gload_lds16(PTR + dRow, lds + (SB) + ldst + 8192);                        \
    PTR += 128;                                                               \
  }
#define STAGEB(PTR, SB, OFF)                                                  \
  {                                                                           \
    gload_lds16(PTR, lds + (SB) + (OFF) + ldst);                              \
    PTR += 128;                                                               \
  }

#define READA(SAB, Q)                                                         \
  {                                                                           \
    const int _o = aOff0 + (Q) * 2048;                                        \
    aR[0] = *(const bf16x8*)(lds + (SAB) + _o);                               \
    aR[1] = *(const bf16x8*)(lds + (SAB) + (_o ^ 64));                        \
  }

#define READBD(SBB)                                                           \
  _Pragma("unroll") for (int n = 0; n < 2; ++n) {                             \
    const int _o = bOff0 + n * 2048;                                          \
    b1R[n][0] = *(const bf16x8*)(lds + (SBB) + _o);                           \
    b1R[n][1] = *(const bf16x8*)(lds + (SBB) + (_o ^ 64));                    \
    b2R[n][0] = *(const bf16x8*)(lds + (SBB) + 8192 + _o);                    \
    b2R[n][1] = *(const bf16x8*)(lds + (SBB) + 8192 + (_o ^ 64));             \
  }

#define MMAD(Q)                                                               \
  __builtin_amdgcn_s_setprio(1);                                              \
  _Pragma("unroll") for (int n = 0; n < 2; ++n)                               \
  _Pragma("unroll") for (int k = 0; k < 2; ++k) {                             \
    acc1[Q][n] = __builtin_amdgcn_mfma_f32_16x16x32_bf16(                     \
        aR[k], b1R[n][k], acc1[Q][n], 0, 0, 0);                               \
    acc2[Q][n] = __builtin_amdgcn_mfma_f32_16x16x32_bf16(                     \
        aR[k], b2R[n][k], acc2[Q][n], 0, 0, 0);                               \
  }                                                                           \
  __builtin_amdgcn_s_setprio(0);

  const int NT = K >> 6;

  // prologue: Bpair(0)->slot0, A0(0)->slot1, A1(0)->slot2
  STAGEB(pB1, 0 * SLOT, 0);
  STAGEB(pB2, 0 * SLOT, 8192);
  STAGEA(pA0, 1 * SLOT);
  STAGEA(pA1, 2 * SLOT);
  asm volatile("s_waitcnt vmcnt(0)" ::: "memory");
  __builtin_amdgcn_s_barrier();

  int iB = 0;   // slot of tile t's Bpair; A0 at iB+1, A1 at iB+2; advance +3

  for (int t = 0; t < NT; ++t) {
    int ib1 = iB + 1 + whalf; if (ib1 >= 5) ib1 -= 5;
    const int sAb = __builtin_amdgcn_readfirstlane(ib1 * SLOT);
    const int sBb = __builtin_amdgcn_readfirstlane(iB * SLOT);
    int i0s = iB + 3; if (i0s >= 5) i0s -= 5;    // Bpair(t+1) -> dead slot
    int i1s = iB + 4; if (i1s >= 5) i1s -= 5;    // A0(t+1)    -> dead slot
    const int s0 = i0s * SLOT, s1 = i1s * SLOT, s2 = iB * SLOT;  // A1(t+1)
    const bool st = (t < NT - 1);
    READBD(sBb);
    READA(sAb, 0);
    if (st) {
      STAGEB(pB1, s0, 0);
      STAGEB(pB2, s0, 8192);
    }
    MMAD(0);
    READA(sAb, 1);
    if (st) STAGEA(pA0, s1);
    MMAD(1);
    READA(sAb, 2);
    MMAD(2);
    // mid barrier: Bpair reads (ph0) + A reads so far complete before s2 reuse
    __builtin_amdgcn_s_barrier();
    READA(sAb, 3);
    if (st) STAGEA(pA1, s2);
    MMAD(3);
    asm volatile("s_waitcnt vmcnt(0)" ::: "memory");
    __builtin_amdgcn_s_barrier();
    iB += 3; if (iB >= 5) iB -= 5;
  }

  // ---- epilogue ----
#pragma unroll
  for (int m = 0; m < 4; ++m) {
#pragma unroll
    for (int n = 0; n < 2; ++n) {
#pragma unroll
      for (int j = 0; j < 4; ++j) {
        const int row = m0 + wrow * 64 + m * 16 + ((lane >> 4) << 2) + j;
        if constexpr (GATED) {
          const int col = n0 + wcol * 32 + n * 16 + (lane & 15);
          const float v1 = acc1[m][n][j] + biasA[col];
          const float v2 = acc2[m][n][j] + biasB[col];
          outH[(size_t)row * N + col] = f2bf(v1 * (v2 / (1.f + __expf(-v2))));
        } else {
#pragma unroll
          for (int s = 0; s < 2; ++s) {
            const int col = n0 + s * 64 + wcol * 32 + n * 16 + (lane & 15);
            const float v = (s == 0 ? acc1[m][n][j] : acc2[m][n][j]) + biasA[col];
            if constexpr (EPI == 5) {
              const int rg = col >> 10;                 // block-uniform group
              const size_t o = (size_t)row * 1024 + (col & 1023);
              if (rg == 0) outH[o] = f2bf(v);
              else if (rg == 1) outH2[o] = f2bf(v);
              else outH3[o] = f2bf(v);
            } else {
              const size_t o = (size_t)row * N + col;
              if constexpr (EPI == 2) {
                const float gt = bf2f(gate[o]);
                outF[o] = v * (gt / (1.f + __expf(-gt))) + resid[o];
              } else if constexpr (EPI == 4) {
                outF[o] = v + outF[o];
              }
            }
          }
        }
      }
    }
  }
#undef STAGEA
#undef STAGEB
#undef READA
#undef READBD
#undef MMAD
}

extern "C" void kernel_launch(void* const* d_in, const int* in_sizes, int n_in,
                              void* d_out, int out_size, void* d_ws, size_t ws_size,
                              hipStream_t stream) {
  const float* x      = (const float*)d_in[0];
  const float* hidden = (const float*)d_in[1];
  const float* w_ln_z = (const float*)d_in[2];
  const float* b_ln_z = (const float*)d_in[3];
  const float* w_dt   = (const float*)d_in[4];
  const float* b_dt   = (const float*)d_in[5];
  const float* w_y    = (const float*)d_in[6];
  const float* b_y    = (const float*)d_in[7];
  const float* w_yg   = (const float*)d_in[8];
  const float* b_yg   = (const float*)d_in[9];
  const float* w_ff   = (const float*)d_in[10];
  const float* b_ff   = (const float*)d_in[11];
  const float* w_ffg  = (const float*)d_in[12];
  const float* b_ffg  = (const float*)d_in[13];
  const float* w_ffo  = (const float*)d_in[14];
  const float* b_ffo  = (const float*)d_in[15];
  const float* g_sio  = (const float*)d_in[16];
  const float* g_ffn  = (const float*)d_in[17];

  char* ws = (char*)d_ws;
  const size_t MB = 1ull << 20;
  u16*   WT_cat = (u16*)(ws + 0 * MB);      // 6 MiB  [3072][1024] (dt|lnz|yg)
  u16*   WT_y   = (u16*)(ws + 8 * MB);      // 2 MiB
  u16*   WT_ff  = (u16*)(ws + 10 * MB);     // 8 MiB  [4096][1024]
  u16*   WT_ffg = (u16*)(ws + 18 * MB);     // 8 MiB
  u16*   WT_ffo = (u16*)(ws + 26 * MB);     // 8 MiB  [1024][4096]
  float* b_cat  = (float*)(ws + 34 * MB);   // 12 KiB [3072]
  u16*   xn     = (u16*)(ws + 36 * MB);     // 32 MiB [16384][1024] bf16
  u16*   dt16   = (u16*)(ws + 68 * MB);     // 32 MiB bf16
  u16*   lnzb   = (u16*)(ws + 100 * MB);    // 32 MiB
  u16*   ygb    = (u16*)(ws + 132 * MB);    // 32 MiB
  u16*   hbf    = (u16*)(ws + 164 * MB);    // 32 MiB
  float* Pc     = (float*)(ws + 196 * MB);  // 1 MiB
  float* Sc     = (float*)(ws + 197 * MB);  // 1 MiB
  float* hin    = (float*)(ws + 198 * MB);  // 1 MiB
  u16*   gs     = (u16*)(ws + 68 * MB);     // 128 MiB overlay [16384][4096]
  // peak ws usage: 199 MiB

  float* x_out = (float*)d_out;
  float* h_out = (float*)d_out + (size_t)4 * 4096 * 1024;

  const int M = 16384, D = 1024, F = 4096;
  const dim3 tb(256);

  transpose_to_bf16<<<dim3(32, 32), tb, 0, stream>>>(w_dt, WT_cat, D, D);
  transpose_to_bf16<<<dim3(32, 32), tb, 0, stream>>>(w_ln_z, WT_cat + 1024 * 1024, D, D);
  transpose_to_bf16<<<dim3(32, 32), tb, 0, stream>>>(w_yg, WT_cat + 2 * 1024 * 1024, D, D);
  transpose_to_bf16<<<dim3(32, 32), tb, 0, stream>>>(w_y, WT_y, D, D);
  transpose_to_bf16<<<dim3(128, 32), tb, 0, stream>>>(w_ff, WT_ff, D, F);
  transpose_to_bf16<<<dim3(128, 32), tb, 0, stream>>>(w_ffg, WT_ffg, D, F);
  transpose_to_bf16<<<dim3(32, 128), tb, 0, stream>>>(w_ffo, WT_ffo, F, D);
  (void)hipMemcpyAsync(b_cat, b_dt, D * 4, hipMemcpyDeviceToDevice, stream);
  (void)hipMemcpyAsync(b_cat + 1024, b_ln_z, D * 4, hipMemcpyDeviceToDevice, stream);
  (void)hipMemcpyAsync(b_cat + 2048, b_yg, D * 4, hipMemcpyDeviceToDevice, stream);

  rmsnorm_kernel<<<M, tb, 0, stream>>>(x, g_sio, xn);

  // fused dt|lnz|yg GEMM (pair mode): N=3072, ntx=24
  gemm_pair<5><<<dim3(64 * 24), 512, 0, stream>>>(
      xn, WT_cat, WT_cat, b_cat, nullptr, nullptr, nullptr,
      nullptr, dt16, lnzb, ygb, 24, 3072, D);

  scan_pass1<<<1024, tb, 0, stream>>>(dt16, lnzb, Pc, Sc);
  scan_pass2<<<16, tb, 0, stream>>>(Pc, Sc, hidden, hin);
  scan_pass3<<<1024, tb, 0, stream>>>(dt16, lnzb, hin, h_out, hbf);

  // x1 = (h@w_y + b_y) * silu(yg) + x   (pair mode, N=1024, ntx=8)
  gemm_pair<2><<<dim3(64 * 8), 512, 0, stream>>>(
      hbf, WT_y, WT_y, b_y, nullptr, ygb, x,
      x_out, nullptr, nullptr, nullptr, 8, D, D);

  rmsnorm_kernel<<<M, tb, 0, stream>>>(x_out, g_ffn, xn);

  // gs = (xn@w_ff + b_ff) * silu(xn@w_ffg + b_ffg)  (gated dual, N=4096, ntx=64)
  gemm_pair<3><<<dim3(64 * 64), 512, 0, stream>>>(
      xn, WT_ff, WT_ffg, b_ff, b_ffg, nullptr, nullptr,
      nullptr, gs, nullptr, nullptr, 64, F, D);

  // x_out += gs@w_ffo + b_ffo   (pair mode, N=1024, ntx=8, K=4096)
  gemm_pair<4><<<dim3(64 * 8), 512, 0, stream>>>(
      gs, WT_ffo, WT_ffo, b_ffo, nullptr, nullptr, nullptr,
      x_out, nullptr, nullptr, nullptr, 8, D, F);
}

// Round 18
// 701.672 us; speedup vs baseline: 1.8970x; 1.0216x over previous
//
#include <hip/hip_runtime.h>
#include <cstdint>
#include <cstddef>

using u16 = unsigned short;
using bf16x8 = __attribute__((ext_vector_type(8))) short;
using f32x4  = __attribute__((ext_vector_type(4))) float;

__device__ __forceinline__ u16 f2bf(float f) {
  unsigned u = __float_as_uint(f);
  u += 0x7fffu + ((u >> 16) & 1u);
  return (u16)(u >> 16);
}
__device__ __forceinline__ float bf2f(u16 h) {
  return __uint_as_float(((unsigned)h) << 16);
}

__device__ __forceinline__ void gload_lds16(const void* g, void* l) {
  auto gp = reinterpret_cast<const __attribute__((address_space(1))) char*>(
      reinterpret_cast<uintptr_t>(g));
  auto lp = reinterpret_cast<__attribute__((address_space(3))) char*>(
      reinterpret_cast<uintptr_t>(l));
  __builtin_amdgcn_global_load_lds(gp, lp, 16, 0, 0);
}

// ---------- batched weight transpose + downcast (z-indexed, up to 4 mats)
__global__ __launch_bounds__(256) void transpose4(
    const float* W0, const float* W1, const float* W2, const float* W3,
    u16* T0, u16* T1, u16* T2, u16* T3, int din, int dout) {
  const float* W; u16* T;
  switch (blockIdx.z) {
    case 0: W = W0; T = T0; break;
    case 1: W = W1; T = T1; break;
    case 2: W = W2; T = T2; break;
    default: W = W3; T = T3; break;
  }
  __shared__ float tile[32][33];
  const int j0 = blockIdx.x * 32;   // dout
  const int i0 = blockIdx.y * 32;   // din
  const int tx = threadIdx.x & 31;
  const int ty = threadIdx.x >> 5;  // 0..7
#pragma unroll
  for (int k = 0; k < 32; k += 8)
    tile[ty + k][tx] = W[(size_t)(i0 + ty + k) * dout + (j0 + tx)];
  __syncthreads();
#pragma unroll
  for (int k = 0; k < 32; k += 8)
    T[(size_t)(j0 + ty + k) * din + (i0 + tx)] = f2bf(tile[tx][ty + k]);
}

// ---------- bias concat: b_cat = [b_dt | b_ln_z | b_yg]
__global__ __launch_bounds__(256) void concat_bias(
    const float* __restrict__ a, const float* __restrict__ b,
    const float* __restrict__ c, float* __restrict__ o) {
  const int i = blockIdx.x * 256 + threadIdx.x;   // grid 12 -> 3072
  o[i] = (i < 1024) ? a[i] : (i < 2048 ? b[i - 1024] : c[i - 2048]);
}

// ---------- rmsnorm f32 -> bf16, one block per row of 1024
__global__ __launch_bounds__(256) void rmsnorm_kernel(
    const float* __restrict__ x, const float* __restrict__ g, u16* __restrict__ xn) {
  const int row = blockIdx.x;
  const float4 v = ((const float4*)(x + (size_t)row * 1024))[threadIdx.x];
  float ss = v.x * v.x + v.y * v.y + v.z * v.z + v.w * v.w;
#pragma unroll
  for (int off = 32; off > 0; off >>= 1) ss += __shfl_down(ss, off, 64);
  __shared__ float red[4];
  if ((threadIdx.x & 63) == 0) red[threadIdx.x >> 6] = ss;
  __syncthreads();
  const float rs = rsqrtf((red[0] + red[1] + red[2] + red[3]) * (1.f / 1024.f) + 1e-6f);
  const float4 gv = ((const float4*)g)[threadIdx.x];
  ushort4 o;
  o.x = f2bf(v.x * rs * gv.x);
  o.y = f2bf(v.y * rs * gv.y);
  o.z = f2bf(v.z * rs * gv.z);
  o.w = f2bf(v.w * rs * gv.w);
  ((ushort4*)(xn + (size_t)row * 1024))[threadIdx.x] = o;
}

// ---------- chunked linear-recurrence scan: h[l] = sig(-dt)*h[l-1] + sig(dt)*sig(lnz)
// P/S layout: channel-major [ch=b*1024+d][chunk] so pass2's per-wave scan
// loads coalesce (lane = chunk).
__global__ __launch_bounds__(256) void scan_pass1(
    const u16* __restrict__ dt, const u16* __restrict__ lnz,
    float* __restrict__ P, float* __restrict__ S) {
  const int blk = blockIdx.x;              // B*64*4 = 1024 blocks
  const int dblk = blk & 3;
  const int chunk = (blk >> 2) & 63;
  const int b = blk >> 8;
  const int d = dblk * 256 + threadIdx.x;
  const size_t base = ((size_t)b * 4096 + (size_t)chunk * 64) * 1024 + d;
  float p = 1.f, s = 0.f;
#pragma unroll 8
  for (int l = 0; l < 64; ++l) {
    const float dtv = bf2f(dt[base + (size_t)l * 1024]);
    const float zv = bf2f(lnz[base + (size_t)l * 1024]);
    const float a = 1.f / (1.f + __expf(dtv));        // sigmoid(-dt)
    const float zs = 1.f / (1.f + __expf(-zv));       // sigmoid(lnz_pre)
    const float in = (1.f - a) * zs;
    p *= a;
    s = a * s + in;
  }
  const size_t o = ((size_t)b * 1024 + d) * 64 + chunk;
  P[o] = p;
  S[o] = s;
}

// pass2: per-wave Hillis-Steele scan over 64 affine maps (one wave = one
// channel). Composition (later∘earlier): P = P_c*P_prev, S = P_c*S_prev + S_c.
// hin[c] = exclusive prefix applied to hidden.
__global__ __launch_bounds__(256) void scan_pass2(
    const float* __restrict__ P, const float* __restrict__ S,
    const float* __restrict__ hidden, float* __restrict__ hin) {
  const int ch = blockIdx.x * 4 + (threadIdx.x >> 6);  // 0..4095
  const int lane = threadIdx.x & 63;
  const size_t base = (size_t)ch * 64;
  float p = P[base + lane];
  float s = S[base + lane];
#pragma unroll
  for (int off = 1; off < 64; off <<= 1) {
    const float pp = __shfl_up(p, off, 64);
    const float sp = __shfl_up(s, off, 64);
    if (lane >= off) { s = p * sp + s; p = p * pp; }
  }
  float pe = __shfl_up(p, 1, 64);
  float se = __shfl_up(s, 1, 64);
  if (lane == 0) { pe = 1.f; se = 0.f; }
  hin[base + lane] = pe * hidden[ch] + se;
}

__global__ __launch_bounds__(256) void scan_pass3(
    const u16* __restrict__ dt, const u16* __restrict__ lnz,
    const float* __restrict__ hin, float* __restrict__ h_out, u16* __restrict__ hbf) {
  const int blk = blockIdx.x;
  const int dblk = blk & 3;
  const int chunk = (blk >> 2) & 63;
  const int b = blk >> 8;
  const int d = dblk * 256 + threadIdx.x;
  const size_t base = ((size_t)b * 4096 + (size_t)chunk * 64) * 1024 + d;
  float h = hin[((size_t)b * 1024 + d) * 64 + chunk];
#pragma unroll 4
  for (int l = 0; l < 64; ++l) {
    const float dtv = bf2f(dt[base + (size_t)l * 1024]);
    const float zv = bf2f(lnz[base + (size_t)l * 1024]);
    const float a = 1.f / (1.f + __expf(dtv));
    const float zs = 1.f / (1.f + __expf(-zv));
    h = a * h + (1.f - a) * zs;
    h_out[base + (size_t)l * 1024] = h;
    hbf[base + (size_t)l * 1024] = f2bf(h);
  }
}

// ---------- PAIR GEMM (R16/R17 keeper): 2 blocks/CU, 8 waves 4Mx2N,
// 80 KiB ring-5, acc1+acc2 = 64 AGPR.
// Modes: EPI==3 gated dual (B1,B2 distinct, same 64 cols);
//        else pair (B2 = B1+64 rows, 128 cols); EPI 5/2/4 epilogues.
template <int EPI>
__global__ __launch_bounds__(512, 4) void gemm_pair(
    const u16* __restrict__ A, const u16* __restrict__ B1, const u16* __restrict__ B2,
    const float* __restrict__ biasA, const float* __restrict__ biasB,
    const u16* __restrict__ gate, const float* __restrict__ resid,
    float* __restrict__ outF, u16* __restrict__ outH,
    u16* __restrict__ outH2, u16* __restrict__ outH3,
    int ntx, int N, int K) {
  constexpr int SLOT = 16384;
  constexpr bool GATED = (EPI == 3);
  const int tid = threadIdx.x;
  const int lane = tid & 63;
  const int wid = tid >> 6;
  const int wrow = wid >> 1;
  const int wcol = wid & 1;
  const int whalf = wrow >> 1;
  const int wsub  = wrow & 1;

  const int nwg = gridDim.x;
  int id = blockIdx.x;
  id = (id & 7) * (nwg >> 3) + (id >> 3);
  const int m0 = (id / ntx) * 256;
  const int n0 = (id % ntx) * (GATED ? 64 : 128);

  __shared__ __align__(16) char lds[5 * SLOT];

  f32x4 acc1[4][2], acc2[4][2];
#pragma unroll
  for (int m = 0; m < 4; ++m)
#pragma unroll
    for (int n = 0; n < 2; ++n) {
      acc1[m][n] = (f32x4){0.f, 0.f, 0.f, 0.f};
      acc2[m][n] = (f32x4){0.f, 0.f, 0.f, 0.f};
    }

  bf16x8 aR[2];
  bf16x8 b1R[2][2], b2R[2][2];

  int aOff0, bOff0;
  {
    const int lq = (lane >> 4) << 4;
    const int ha = wsub * 64 + (lane & 15);
    aOff0 = ha * 128 + (lq ^ ((ha & 7) << 4));
    const int hb = wcol * 32 + (lane & 15);
    bOff0 = hb * 128 + (lq ^ ((hb & 7) << 4));
  }

  const int row0 = tid >> 3;
  const int kb0  = ((tid & 7) * 16) ^ ((row0 & 7) << 4);
  const size_t dRow = (size_t)128 * K;
  const char* pA0 = (const char*)A + (size_t)(m0 + row0) * K * 2 + kb0;
  const char* pA1 = pA0 + (size_t)256 * K;
  const char* pB1 = (const char*)B1 + (size_t)(n0 + row0) * K * 2 + kb0;
  const char* pB2 = (const char*)B2 +
                    (size_t)((GATED ? n0 : n0 + 64) + row0) * K * 2 + kb0;
  const int ldst = tid * 16;

#define STAGEA(PTR, SB)                                                       \
  {                                                                           \
    gload_lds16(PTR, lds + (SB) + ldst);                                      \
    gload_lds16(PTR + dRow, lds + (SB) + ldst + 8192);                        \
    PTR += 128;                                                               \
  }
#define STAGEB(PTR, SB, OFF)                                                  \
  {                                                                           \
    gload_lds16(PTR, lds + (SB) + (OFF) + ldst);                              \
    PTR += 128;                                                               \
  }

#define READA(SAB, Q)                                                         \
  {                                                                           \
    const int _o = aOff0 + (Q) * 2048;                                        \
    aR[0] = *(const bf16x8*)(lds + (SAB) + _o);                               \
    aR[1] = *(const bf16x8*)(lds + (SAB) + (_o ^ 64));                        \
  }

#define READBD(SBB)                                                           \
  _Pragma("unroll") for (int n = 0; n < 2; ++n) {                             \
    const int _o = bOff0 + n * 2048;                                          \
    b1R[n][0] = *(const bf16x8*)(lds + (SBB) + _o);                           \
    b1R[n][1] = *(const bf16x8*)(lds + (SBB) + (_o ^ 64));                    \
    b2R[n][0] = *(const bf16x8*)(lds + (SBB) + 8192 + _o);                    \
    b2R[n][1] = *(const bf16x8*)(lds + (SBB) + 8192 + (_o ^ 64));             \
  }

#define MMAD(Q)                                                               \
  __builtin_amdgcn_s_setprio(1);                                              \
  _Pragma("unroll") for (int n = 0; n < 2; ++n)                               \
  _Pragma("unroll") for (int k = 0; k < 2; ++k) {                             \
    acc1[Q][n] = __builtin_amdgcn_mfma_f32_16x16x32_bf16(                     \
        aR[k], b1R[n][k], acc1[Q][n], 0, 0, 0);                               \
    acc2[Q][n] = __builtin_amdgcn_mfma_f32_16x16x32_bf16(                     \
        aR[k], b2R[n][k], acc2[Q][n], 0, 0, 0);                               \
  }                                                                           \
  __builtin_amdgcn_s_setprio(0);

  const int NT = K >> 6;

  STAGEB(pB1, 0 * SLOT, 0);
  STAGEB(pB2, 0 * SLOT, 8192);
  STAGEA(pA0, 1 * SLOT);
  STAGEA(pA1, 2 * SLOT);
  asm volatile("s_waitcnt vmcnt(0)" ::: "memory");
  __builtin_amdgcn_s_barrier();

  int iB = 0;

  for (int t = 0; t < NT; ++t) {
    int ib1 = iB + 1 + whalf; if (ib1 >= 5) ib1 -= 5;
    const int sAb = __builtin_amdgcn_readfirstlane(ib1 * SLOT);
    const int sBb = __builtin_amdgcn_readfirstlane(iB * SLOT);
    int i0s = iB + 3; if (i0s >= 5) i0s -= 5;
    int i1s = iB + 4; if (i1s >= 5) i1s -= 5;
    const int s0 = i0s * SLOT, s1 = i1s * SLOT, s2 = iB * SLOT;
    const bool st = (t < NT - 1);
    READBD(sBb);
    READA(sAb, 0);
    if (st) {
      STAGEB(pB1, s0, 0);
      STAGEB(pB2, s0, 8192);
    }
    MMAD(0);
    READA(sAb, 1);
    if (st) STAGEA(pA0, s1);
    MMAD(1);
    READA(sAb, 2);
    MMAD(2);
    __builtin_amdgcn_s_barrier();
    READA(sAb, 3);
    if (st) STAGEA(pA1, s2);
    MMAD(3);
    asm volatile("s_waitcnt vmcnt(0)" ::: "memory");
    __builtin_amdgcn_s_barrier();
    iB += 3; if (iB >= 5) iB -= 5;
  }

#pragma unroll
  for (int m = 0; m < 4; ++m) {
#pragma unroll
    for (int n = 0; n < 2; ++n) {
#pragma unroll
      for (int j = 0; j < 4; ++j) {
        const int row = m0 + wrow * 64 + m * 16 + ((lane >> 4) << 2) + j;
        if constexpr (GATED) {
          const int col = n0 + wcol * 32 + n * 16 + (lane & 15);
          const float v1 = acc1[m][n][j] + biasA[col];
          const float v2 = acc2[m][n][j] + biasB[col];
          outH[(size_t)row * N + col] = f2bf(v1 * (v2 / (1.f + __expf(-v2))));
        } else {
#pragma unroll
          for (int s = 0; s < 2; ++s) {
            const int col = n0 + s * 64 + wcol * 32 + n * 16 + (lane & 15);
            const float v = (s == 0 ? acc1[m][n][j] : acc2[m][n][j]) + biasA[col];
            if constexpr (EPI == 5) {
              const int rg = col >> 10;
              const size_t o = (size_t)row * 1024 + (col & 1023);
              if (rg == 0) outH[o] = f2bf(v);
              else if (rg == 1) outH2[o] = f2bf(v);
              else outH3[o] = f2bf(v);
            } else {
              const size_t o = (size_t)row * N + col;
              if constexpr (EPI == 2) {
                const float gt = bf2f(gate[o]);
                outF[o] = v * (gt / (1.f + __expf(-gt))) + resid[o];
              } else if constexpr (EPI == 4) {
                outF[o] = v + outF[o];
              }
            }
          }
        }
      }
    }
  }
#undef STAGEA
#undef STAGEB
#undef READA
#undef READBD
#undef MMAD
}

extern "C" void kernel_launch(void* const* d_in, const int* in_sizes, int n_in,
                              void* d_out, int out_size, void* d_ws, size_t ws_size,
                              hipStream_t stream) {
  const float* x      = (const float*)d_in[0];
  const float* hidden = (const float*)d_in[1];
  const float* w_ln_z = (const float*)d_in[2];
  const float* b_ln_z = (const float*)d_in[3];
  const float* w_dt   = (const float*)d_in[4];
  const float* b_dt   = (const float*)d_in[5];
  const float* w_y    = (const float*)d_in[6];
  const float* b_y    = (const float*)d_in[7];
  const float* w_yg   = (const float*)d_in[8];
  const float* b_yg   = (const float*)d_in[9];
  const float* w_ff   = (const float*)d_in[10];
  const float* b_ff   = (const float*)d_in[11];
  const float* w_ffg  = (const float*)d_in[12];
  const float* b_ffg  = (const float*)d_in[13];
  const float* w_ffo  = (const float*)d_in[14];
  const float* b_ffo  = (const float*)d_in[15];
  const float* g_sio  = (const float*)d_in[16];
  const float* g_ffn  = (const float*)d_in[17];

  char* ws = (char*)d_ws;
  const size_t MB = 1ull << 20;
  u16*   WT_cat = (u16*)(ws + 0 * MB);      // 6 MiB  [3072][1024] (dt|lnz|yg)
  u16*   WT_y   = (u16*)(ws + 8 * MB);      // 2 MiB
  u16*   WT_ff  = (u16*)(ws + 10 * MB);     // 8 MiB  [4096][1024]
  u16*   WT_ffg = (u16*)(ws + 18 * MB);     // 8 MiB
  u16*   WT_ffo = (u16*)(ws + 26 * MB);     // 8 MiB  [1024][4096]
  float* b_cat  = (float*)(ws + 34 * MB);   // 12 KiB [3072]
  u16*   xn     = (u16*)(ws + 36 * MB);     // 32 MiB [16384][1024] bf16
  u16*   dt16   = (u16*)(ws + 68 * MB);     // 32 MiB bf16
  u16*   lnzb   = (u16*)(ws + 100 * MB);    // 32 MiB
  u16*   ygb    = (u16*)(ws + 132 * MB);    // 32 MiB
  u16*   hbf    = (u16*)(ws + 164 * MB);    // 32 MiB
  float* Pc     = (float*)(ws + 196 * MB);  // 1 MiB  (channel-major [4096][64])
  float* Sc     = (float*)(ws + 197 * MB);  // 1 MiB
  float* hin    = (float*)(ws + 198 * MB);  // 1 MiB
  u16*   gs     = (u16*)(ws + 68 * MB);     // 128 MiB overlay [16384][4096]
  // peak ws usage: 199 MiB

  float* x_out = (float*)d_out;
  float* h_out = (float*)d_out + (size_t)4 * 4096 * 1024;

  const int M = 16384, D = 1024, F = 4096;
  const dim3 tb(256);

  // batched transposes: 4x DxD, 2x DxF, 1x FxD
  transpose4<<<dim3(32, 32, 4), tb, 0, stream>>>(
      w_dt, w_ln_z, w_yg, w_y,
      WT_cat, WT_cat + 1024 * 1024, WT_cat + 2 * 1024 * 1024, WT_y, D, D);
  transpose4<<<dim3(128, 32, 2), tb, 0, stream>>>(
      w_ff, w_ffg, w_ff, w_ffg, WT_ff, WT_ffg, WT_ff, WT_ffg, D, F);
  transpose4<<<dim3(32, 128, 1), tb, 0, stream>>>(
      w_ffo, w_ffo, w_ffo, w_ffo, WT_ffo, WT_ffo, WT_ffo, WT_ffo, F, D);
  concat_bias<<<12, tb, 0, stream>>>(b_dt, b_ln_z, b_yg, b_cat);

  rmsnorm_kernel<<<M, tb, 0, stream>>>(x, g_sio, xn);

  // fused dt|lnz|yg GEMM (pair mode): N=3072, ntx=24
  gemm_pair<5><<<dim3(64 * 24), 512, 0, stream>>>(
      xn, WT_cat, WT_cat, b_cat, nullptr, nullptr, nullptr,
      nullptr, dt16, lnzb, ygb, 24, 3072, D);

  scan_pass1<<<1024, tb, 0, stream>>>(dt16, lnzb, Pc, Sc);
  scan_pass2<<<1024, tb, 0, stream>>>(Pc, Sc, hidden, hin);
  scan_pass3<<<1024, tb, 0, stream>>>(dt16, lnzb, hin, h_out, hbf);

  // x1 = (h@w_y + b_y) * silu(yg) + x   (pair mode, N=1024, ntx=8)
  gemm_pair<2><<<dim3(64 * 8), 512, 0, stream>>>(
      hbf, WT_y, WT_y, b_y, nullptr, ygb, x,
      x_out, nullptr, nullptr, nullptr, 8, D, D);

  rmsnorm_kernel<<<M, tb, 0, stream>>>(x_out, g_ffn, xn);

  // gs = (xn@w_ff + b_ff) * silu(xn@w_ffg + b_ffg)  (gated dual, N=4096, ntx=64)
  gemm_pair<3><<<dim3(64 * 64), 512, 0, stream>>>(
      xn, WT_ff, WT_ffg, b_ff, b_ffg, nullptr, nullptr,
      nullptr, gs, nullptr, nullptr, 64, F, D);

  // x_out += gs@w_ffo + b_ffo   (pair mode, N=1024, ntx=8, K=4096)
  gemm_pair<4><<<dim3(64 * 8), 512, 0, stream>>>(
      gs, WT_ffo, WT_ffo, b_ffo, nullptr, nullptr, nullptr,
      x_out, nullptr, nullptr, nullptr, 8, D, F);
}